// Round 1
// baseline (2050.662 us; speedup 1.0000x reference)
//
#include <hip/hip_runtime.h>
#include <hip/hip_bf16.h>
#include <math.h>

#define EPS 1e-6f

// ---------------------------------------------------------------------------
// GEMM: C[M,N] = A[M,K] @ B[K,N], row-major f32.
// BM=BN=64, BK=16, 256 threads, each thread computes a 4x4 micro-tile.
// M % 64 == 0, N % 64 == 0, K % 16 == 0 (true for all shapes here).
// ---------------------------------------------------------------------------
__global__ __launch_bounds__(256) void gemm_f32(const float* __restrict__ A,
                                                const float* __restrict__ B,
                                                float* __restrict__ C,
                                                int M, int N, int K) {
    __shared__ float As[16][68];  // [k][m], +4 pad keeps float4 alignment & banks spread
    __shared__ float Bs[16][64];  // [k][n]

    const int tid = threadIdx.x;
    const int tx = tid & 15;   // n-group (4 cols each)
    const int ty = tid >> 4;   // m-group (4 rows each)
    const int brow = blockIdx.y * 64;
    const int bcol = blockIdx.x * 64;

    float acc[4][4] = {};

    for (int k0 = 0; k0 < K; k0 += 16) {
        // --- stage A tile (64 rows x 16 k) ---
        {
            const int m  = tid >> 2;
            const int kk = (tid & 3) * 4;
            const float4 a = *reinterpret_cast<const float4*>(
                &A[(size_t)(brow + m) * K + k0 + kk]);
            As[kk + 0][m] = a.x;
            As[kk + 1][m] = a.y;
            As[kk + 2][m] = a.z;
            As[kk + 3][m] = a.w;
        }
        // --- stage B tile (16 k x 64 cols) ---
        {
            const int kk = tid >> 4;
            const int n4 = (tid & 15) * 4;
            *reinterpret_cast<float4*>(&Bs[kk][n4]) =
                *reinterpret_cast<const float4*>(
                    &B[(size_t)(k0 + kk) * N + bcol + n4]);
        }
        __syncthreads();

        #pragma unroll
        for (int kk = 0; kk < 16; ++kk) {
            const float4 a = *reinterpret_cast<const float4*>(&As[kk][ty * 4]);
            const float4 b = *reinterpret_cast<const float4*>(&Bs[kk][tx * 4]);
            acc[0][0] += a.x * b.x; acc[0][1] += a.x * b.y; acc[0][2] += a.x * b.z; acc[0][3] += a.x * b.w;
            acc[1][0] += a.y * b.x; acc[1][1] += a.y * b.y; acc[1][2] += a.y * b.z; acc[1][3] += a.y * b.w;
            acc[2][0] += a.z * b.x; acc[2][1] += a.z * b.y; acc[2][2] += a.z * b.z; acc[2][3] += a.z * b.w;
            acc[3][0] += a.w * b.x; acc[3][1] += a.w * b.y; acc[3][2] += a.w * b.z; acc[3][3] += a.w * b.w;
        }
        __syncthreads();
    }

    #pragma unroll
    for (int i = 0; i < 4; ++i) {
        float4 o;
        o.x = acc[i][0]; o.y = acc[i][1]; o.z = acc[i][2]; o.w = acc[i][3];
        *reinterpret_cast<float4*>(
            &C[(size_t)(brow + ty * 4 + i) * N + bcol + tx * 4]) = o;
    }
}

// ---------------------------------------------------------------------------
// Fused RoPE + RMSNorm(noscale) over q (B,T,16,64) and k (B,T,4,64), in place.
// One 64-lane wave per head-row; 4 rows per 256-thread block.
// Reference rope: y1 = x1*cos + x2*sin ; y2 = -x1*sin + x2*cos  (d = 32 halves)
// ---------------------------------------------------------------------------
__global__ __launch_bounds__(256) void rope_rmsnorm(float* __restrict__ q,
                                                    float* __restrict__ k,
                                                    const float* __restrict__ cosb,
                                                    const float* __restrict__ sinb,
                                                    int B, int T) {
    const int lane = threadIdx.x & 63;
    const int wid  = threadIdx.x >> 6;
    const int row  = blockIdx.x * 4 + wid;   // over B*T*20 rows (16 q + 4 k heads)
    const int bt = row / 20;
    const int h  = row % 20;
    const int t  = bt % T;

    float* ptr = (h < 16) ? q + ((size_t)bt * 16 + h) * 64
                          : k + ((size_t)bt * 4 + (h - 16)) * 64;

    const int j = lane & 31;
    const float x1 = ptr[j];
    const float x2 = ptr[j + 32];
    const float c = cosb[t * 32 + j];
    const float s = sinb[t * 32 + j];
    float y = (lane < 32) ? (x1 * c + x2 * s) : (x2 * c - x1 * s);

    float ss = y * y;
    #pragma unroll
    for (int m = 1; m < 64; m <<= 1) ss += __shfl_xor(ss, m);
    const float r = rsqrtf(ss * (1.0f / 64.0f) + EPS);
    ptr[lane] = y * r;
}

// ---------------------------------------------------------------------------
// Causal GQA attention, flash-style online softmax, f32.
// Grid: (T/4, N_HEAD, B). Block: 256 threads = 4 waves; wave w handles query
// row t = blockIdx.x*4 + w. K/V staged in LDS tiles of 64 keys.
// Phase 1 (lane = key): score via serial dot over 64 dims (q in registers).
// Phase 2 (lane = dim): y[d] += p[s] * v[s][d], p broadcast via __shfl.
// ---------------------------------------------------------------------------
__global__ __launch_bounds__(256) void attn_fwd(const float* __restrict__ q,
                                                const float* __restrict__ k,
                                                const float* __restrict__ v,
                                                float* __restrict__ att,
                                                int B, int T) {
    __shared__ float kt[64][65];   // (s+d)%32 banks -> 2-way (free)
    __shared__ float vt[64][65];

    const int tid  = threadIdx.x;
    const int lane = tid & 63;
    const int w    = tid >> 6;
    const int h  = blockIdx.y;
    const int b  = blockIdx.z;
    const int hk = h >> 2;                 // GQA: 4 q-heads per kv-head
    const int t  = blockIdx.x * 4 + w;

    // q row -> registers, pre-scaled by 1/sqrt(64). Lane-uniform addresses.
    const float* qrow = q + (((size_t)b * T + t) * 16 + h) * 64;
    float qr[64];
    #pragma unroll
    for (int d = 0; d < 64; ++d) qr[d] = qrow[d] * 0.125f;

    float m = -INFINITY, l = 0.f, acc = 0.f;
    const int nt = (t >> 6) + 1;   // identical for all 4 waves (4 | 64)

    for (int ti = 0; ti < nt; ++ti) {
        const int s0 = ti << 6;
        __syncthreads();
        // stage K/V tiles (64 keys x 64 dims), float4 global loads
        #pragma unroll
        for (int i = 0; i < 4; ++i) {
            const int s  = (tid >> 4) + i * 16;
            const int d4 = (tid & 15) * 4;
            const size_t kvbase = (((size_t)b * T + s0 + s) * 4 + hk) * 64 + d4;
            const float4 kk4 = *reinterpret_cast<const float4*>(&k[kvbase]);
            kt[s][d4 + 0] = kk4.x; kt[s][d4 + 1] = kk4.y;
            kt[s][d4 + 2] = kk4.z; kt[s][d4 + 3] = kk4.w;
            const float4 vv4 = *reinterpret_cast<const float4*>(&v[kvbase]);
            vt[s][d4 + 0] = vv4.x; vt[s][d4 + 1] = vv4.y;
            vt[s][d4 + 2] = vv4.z; vt[s][d4 + 3] = vv4.w;
        }
        __syncthreads();

        // ---- phase 1: lane = key index within tile ----
        const int s = s0 + lane;
        float sc = -1e30f;
        if (s <= t) {
            float dot = 0.f;
            #pragma unroll
            for (int d = 0; d < 64; ++d) dot += qr[d] * kt[lane][d];
            sc = dot;
        }
        float tm = sc;
        #pragma unroll
        for (int mm = 1; mm < 64; mm <<= 1) tm = fmaxf(tm, __shfl_xor(tm, mm));
        const float mn = fmaxf(m, tm);
        const float f  = __expf(m - mn);          // first tile: exp(-inf)=0
        const float p  = (s <= t) ? __expf(sc - mn) : 0.f;
        float sp = p;
        #pragma unroll
        for (int mm = 1; mm < 64; mm <<= 1) sp += __shfl_xor(sp, mm);
        l = l * f + sp;
        acc *= f;
        m = mn;

        // ---- phase 2: lane = output dim ----
        #pragma unroll
        for (int s2 = 0; s2 < 64; ++s2)
            acc += __shfl(p, s2) * vt[s2][lane];
    }

    att[(((size_t)b * T + t) * 16 + h) * 64 + lane] = acc / l;
}

// ---------------------------------------------------------------------------
extern "C" void kernel_launch(void* const* d_in, const int* in_sizes, int n_in,
                              void* d_out, int out_size, void* d_ws, size_t ws_size,
                              hipStream_t stream) {
    const float* x    = (const float*)d_in[0];
    const float* cosb = (const float*)d_in[1];
    const float* sinb = (const float*)d_in[2];
    const float* Wq   = (const float*)d_in[3];
    const float* Wk   = (const float*)d_in[4];
    const float* Wv   = (const float*)d_in[5];
    const float* Wo   = (const float*)d_in[6];
    float* out = (float*)d_out;

    const int B = 2, T = 2048;
    const int M = B * T;             // 4096 rows

    float* qb  = (float*)d_ws;                       // M*1024 f32 = 16 MB
    float* kb  = qb + (size_t)M * 1024;              // M*256       = 4 MB
    float* vb  = kb + (size_t)M * 256;               // M*256       = 4 MB
    float* att = vb + (size_t)M * 256;               // M*1024      = 16 MB

    // QKV projections
    gemm_f32<<<dim3(1024 / 64, M / 64), 256, 0, stream>>>(x, Wq, qb, M, 1024, 1024);
    gemm_f32<<<dim3(256 / 64,  M / 64), 256, 0, stream>>>(x, Wk, kb, M, 256, 1024);
    gemm_f32<<<dim3(256 / 64,  M / 64), 256, 0, stream>>>(x, Wv, vb, M, 256, 1024);

    // RoPE + RMSNorm in place on q,k
    rope_rmsnorm<<<(B * T * 20) / 4, 256, 0, stream>>>(qb, kb, cosb, sinb, B, T);

    // causal GQA attention -> att (B,T,16,64) laid out as (B,T,1024)
    attn_fwd<<<dim3(T / 4, 16, B), 256, 0, stream>>>(qb, kb, vb, att, B, T);

    // output projection
    gemm_f32<<<dim3(1024 / 64, M / 64), 256, 0, stream>>>(att, Wo, out, M, 1024, 1024);
}

// Round 2
// 511.338 us; speedup vs baseline: 4.0104x; 4.0104x over previous
//
#include <hip/hip_runtime.h>
#include <hip/hip_bf16.h>
#include <math.h>

#define EPS 1e-6f

typedef __attribute__((ext_vector_type(8))) short short8;
typedef __attribute__((ext_vector_type(4))) short short4v;
typedef __attribute__((ext_vector_type(4))) float f32x4;

// f32 -> bf16 (round-to-nearest-even), self-contained
static __device__ __forceinline__ short f2bf(float x) {
    unsigned u = __builtin_bit_cast(unsigned, x);
    u += 0x7fffu + ((u >> 16) & 1u);
    return (short)(u >> 16);
}

// ---------------------------------------------------------------------------
// GEMM: C[M,N] = A[M,K] @ B[K,N], row-major f32. (unchanged from round 1)
// ---------------------------------------------------------------------------
__global__ __launch_bounds__(256) void gemm_f32(const float* __restrict__ A,
                                                const float* __restrict__ B,
                                                float* __restrict__ C,
                                                int M, int N, int K) {
    __shared__ float As[16][68];
    __shared__ float Bs[16][64];

    const int tid = threadIdx.x;
    const int tx = tid & 15;
    const int ty = tid >> 4;
    const int brow = blockIdx.y * 64;
    const int bcol = blockIdx.x * 64;

    float acc[4][4] = {};

    for (int k0 = 0; k0 < K; k0 += 16) {
        {
            const int m  = tid >> 2;
            const int kk = (tid & 3) * 4;
            const float4 a = *reinterpret_cast<const float4*>(
                &A[(size_t)(brow + m) * K + k0 + kk]);
            As[kk + 0][m] = a.x;
            As[kk + 1][m] = a.y;
            As[kk + 2][m] = a.z;
            As[kk + 3][m] = a.w;
        }
        {
            const int kk = tid >> 4;
            const int n4 = (tid & 15) * 4;
            *reinterpret_cast<float4*>(&Bs[kk][n4]) =
                *reinterpret_cast<const float4*>(
                    &B[(size_t)(k0 + kk) * N + bcol + n4]);
        }
        __syncthreads();

        #pragma unroll
        for (int kk = 0; kk < 16; ++kk) {
            const float4 a = *reinterpret_cast<const float4*>(&As[kk][ty * 4]);
            const float4 b = *reinterpret_cast<const float4*>(&Bs[kk][tx * 4]);
            acc[0][0] += a.x * b.x; acc[0][1] += a.x * b.y; acc[0][2] += a.x * b.z; acc[0][3] += a.x * b.w;
            acc[1][0] += a.y * b.x; acc[1][1] += a.y * b.y; acc[1][2] += a.y * b.z; acc[1][3] += a.y * b.w;
            acc[2][0] += a.z * b.x; acc[2][1] += a.z * b.y; acc[2][2] += a.z * b.z; acc[2][3] += a.z * b.w;
            acc[3][0] += a.w * b.x; acc[3][1] += a.w * b.y; acc[3][2] += a.w * b.z; acc[3][3] += a.w * b.w;
        }
        __syncthreads();
    }

    #pragma unroll
    for (int i = 0; i < 4; ++i) {
        float4 o;
        o.x = acc[i][0]; o.y = acc[i][1]; o.z = acc[i][2]; o.w = acc[i][3];
        *reinterpret_cast<float4*>(
            &C[(size_t)(brow + ty * 4 + i) * N + bcol + tx * 4]) = o;
    }
}

// ---------------------------------------------------------------------------
// RoPE + RMSNorm on q,k (f32 in) -> bf16 out, head-major layouts.
//   q16: [B,16,T,64]   (softmax scale 0.125 folded into q)
//   k16: [B, 4,T,64]
// One wave per head-row; 4 rows per block; rows ordered (b,t,h) h=0..19.
// ---------------------------------------------------------------------------
__global__ __launch_bounds__(256) void rope_rmsnorm_cast(
    const float* __restrict__ qf, const float* __restrict__ kf,
    const float* __restrict__ cosb, const float* __restrict__ sinb,
    short* __restrict__ q16, short* __restrict__ k16, int B, int T) {
    const int lane = threadIdx.x & 63;
    const int wid  = threadIdx.x >> 6;
    const int row  = blockIdx.x * 4 + wid;
    const int bt = row / 20;
    const int h  = row % 20;
    const int b  = bt / T, t = bt % T;

    const float* src = (h < 16) ? qf + ((size_t)bt * 16 + h) * 64
                                : kf + ((size_t)bt * 4 + (h - 16)) * 64;

    const int j = lane & 31;
    const float x1 = src[j];
    const float x2 = src[j + 32];
    const float c = cosb[t * 32 + j];
    const float s = sinb[t * 32 + j];
    float y = (lane < 32) ? (x1 * c + x2 * s) : (x2 * c - x1 * s);

    float ss = y * y;
    #pragma unroll
    for (int m = 1; m < 64; m <<= 1) ss += __shfl_xor(ss, m);
    const float r = rsqrtf(ss * (1.0f / 64.0f) + EPS);

    if (h < 16)
        q16[((size_t)(b * 16 + h) * T + t) * 64 + lane] = f2bf(y * r * 0.125f);
    else
        k16[((size_t)(b * 4 + (h - 16)) * T + t) * 64 + lane] = f2bf(y * r);
}

// ---------------------------------------------------------------------------
// v (f32 [B,T,4,64]) -> bf16 transposed vT16 [B,4,64,T]
// Block: 64 t-rows x 64 dims tile. LDS transpose, coalesced in and out.
// ---------------------------------------------------------------------------
__global__ __launch_bounds__(256) void vcast_transpose(
    const float* __restrict__ vb, short* __restrict__ vT, int B, int T) {
    __shared__ short tl[64][65];
    const int tid = threadIdx.x;
    const int b = blockIdx.z, kvh = blockIdx.y, t0 = blockIdx.x * 64;

    #pragma unroll
    for (int i = 0; i < 4; ++i) {
        const int tr = (tid >> 4) + i * 16;
        const int d4 = (tid & 15) * 4;
        const float4 v4 = *reinterpret_cast<const float4*>(
            &vb[(((size_t)b * T + t0 + tr) * 4 + kvh) * 64 + d4]);
        tl[tr][d4 + 0] = f2bf(v4.x);
        tl[tr][d4 + 1] = f2bf(v4.y);
        tl[tr][d4 + 2] = f2bf(v4.z);
        tl[tr][d4 + 3] = f2bf(v4.w);
    }
    __syncthreads();

    const int dim = tid >> 2;
    const int tq  = (tid & 3) * 16;
    short tmp[16];
    #pragma unroll
    for (int j2 = 0; j2 < 16; ++j2) tmp[j2] = tl[tq + j2][dim];
    short8* outp = reinterpret_cast<short8*>(
        &vT[((size_t)(b * 4 + kvh) * 64 + dim) * T + t0 + tq]);
    outp[0] = *reinterpret_cast<short8*>(&tmp[0]);
    outp[1] = *reinterpret_cast<short8*>(&tmp[8]);
}

// ---------------------------------------------------------------------------
// bf16 MFMA flash attention (causal, GQA 4:1), D=64.
// Grid (T/64, 16, B); block = 4 waves; wave w owns 16 q-rows t0w..t0w+15.
// S^T = K·Q^T via mfma_16x16x32_bf16 -> lane holds P at q=lane&15 ->
// PV consumes P in-register (custom bijective k-map on both operands).
// K tile [64s][64d], V^T tile [64d][64s] in LDS, 16B-chunk XOR swizzle.
// ---------------------------------------------------------------------------
__global__ __launch_bounds__(256) void attn_mfma(
    const short* __restrict__ q16, const short* __restrict__ k16,
    const short* __restrict__ vT16, float* __restrict__ att, int B, int T) {
    __shared__ short Kt[64 * 64];
    __shared__ short Vt[64 * 64];

    const int tid  = threadIdx.x;
    const int lane = tid & 63;
    const int w    = tid >> 6;
    const int lq   = lane & 15;   // q column
    const int lh   = lane >> 4;   // k-group
    const int qb = blockIdx.x, h = blockIdx.y, b = blockIdx.z;
    const int hk = h >> 2;
    const int t0w = qb * 64 + w * 16;

    // Q fragments (global, hoisted). q row = t0w + lq, 8 contiguous d at lh*8.
    const short* qrow = q16 + ((size_t)(b * 16 + h) * T + t0w + lq) * 64;
    const short8 qf0 = *reinterpret_cast<const short8*>(qrow + lh * 8);
    const short8 qf1 = *reinterpret_cast<const short8*>(qrow + 32 + lh * 8);

    const short* kgbase = k16 + (size_t)(b * 4 + hk) * T * 64;
    const short* vgbase = vT16 + (size_t)(b * 4 + hk) * 64 * T;

    f32x4 yacc[4];
    #pragma unroll
    for (int dt = 0; dt < 4; ++dt) yacc[dt] = (f32x4){0.f, 0.f, 0.f, 0.f};
    float mrun = -1e30f, lrun = 0.f;

    for (int ti = 0; ti <= qb; ++ti) {
        const int s0 = ti * 64;
        __syncthreads();
        // --- stage K tile and V^T tile, 16B chunks, XOR swizzle c^(r&7) ---
        #pragma unroll
        for (int i = 0; i < 2; ++i) {
            const int cid = tid + i * 256;
            const int r = cid >> 3, c = cid & 7;
            const short8 kv = *reinterpret_cast<const short8*>(
                kgbase + (size_t)(s0 + r) * 64 + c * 8);
            *reinterpret_cast<short8*>(
                (char*)Kt + r * 128 + ((c ^ (r & 7)) * 16)) = kv;
            const short8 vv = *reinterpret_cast<const short8*>(
                vgbase + (size_t)r * T + s0 + c * 8);
            *reinterpret_cast<short8*>(
                (char*)Vt + r * 128 + ((c ^ (r & 7)) * 16)) = vv;
        }
        __syncthreads();

        // --- QK^T: S^T[s][q], 4 key-subtiles x 2 k-steps ---
        f32x4 st[4];
        #pragma unroll
        for (int ks = 0; ks < 4; ++ks) {
            f32x4 acc = (f32x4){0.f, 0.f, 0.f, 0.f};
            #pragma unroll
            for (int dk = 0; dk < 2; ++dk) {
                const short8 kfr = *reinterpret_cast<const short8*>(
                    (char*)Kt + (ks * 16 + lq) * 128 +
                    (((dk * 4 + lh) ^ (lq & 7)) * 16));
                acc = __builtin_amdgcn_mfma_f32_16x16x32_bf16(
                    kfr, dk ? qf1 : qf0, acc, 0, 0, 0);
            }
            st[ks] = acc;
        }

        // --- causal mask on diagonal tile ---
        if (ti == qb) {
            #pragma unroll
            for (int ks = 0; ks < 4; ++ks)
                #pragma unroll
                for (int i2 = 0; i2 < 4; ++i2)
                    if (ks * 16 + lh * 4 + i2 > w * 16 + lq)
                        st[ks][i2] = -1e30f;
        }

        // --- online softmax (row = q = lq; reduce over lh via shfl) ---
        float pm = -1e30f;
        #pragma unroll
        for (int ks = 0; ks < 4; ++ks)
            #pragma unroll
            for (int i2 = 0; i2 < 4; ++i2) pm = fmaxf(pm, st[ks][i2]);
        pm = fmaxf(pm, __shfl_xor(pm, 16));
        pm = fmaxf(pm, __shfl_xor(pm, 32));
        const float mn  = fmaxf(mrun, pm);
        const float fsc = __expf(mrun - mn);
        float ps = 0.f;
        #pragma unroll
        for (int ks = 0; ks < 4; ++ks)
            #pragma unroll
            for (int i2 = 0; i2 < 4; ++i2) {
                const float p = __expf(st[ks][i2] - mn);
                st[ks][i2] = p;
                ps += p;
            }
        ps += __shfl_xor(ps, 16);
        ps += __shfl_xor(ps, 32);
        lrun = lrun * fsc + ps;
        mrun = mn;
        #pragma unroll
        for (int dt = 0; dt < 4; ++dt) yacc[dt] *= fsc;

        // --- P -> bf16 fragments (in-register; k-map 16*(j>>2)+lh*4+(j&3)) ---
        short8 pfrag[2];
        #pragma unroll
        for (int ks2 = 0; ks2 < 2; ++ks2) {
            short8 pb;
            pb[0] = f2bf(st[2 * ks2][0]);
            pb[1] = f2bf(st[2 * ks2][1]);
            pb[2] = f2bf(st[2 * ks2][2]);
            pb[3] = f2bf(st[2 * ks2][3]);
            pb[4] = f2bf(st[2 * ks2 + 1][0]);
            pb[5] = f2bf(st[2 * ks2 + 1][1]);
            pb[6] = f2bf(st[2 * ks2 + 1][2]);
            pb[7] = f2bf(st[2 * ks2 + 1][3]);
            pfrag[ks2] = pb;
        }

        // --- PV: Y^T[dim][q] += V^T-frag · P-frag (same k-map both sides) ---
        #pragma unroll
        for (int dt = 0; dt < 4; ++dt) {
            const int rb = (dt * 16 + lq) * 128;
            const int sw = lq & 7;
            #pragma unroll
            for (int ks2 = 0; ks2 < 2; ++ks2) {
                const int c0 = ks2 * 4 + (lh >> 1);
                const int h8 = (lh & 1) * 8;
                const short4v lo = *reinterpret_cast<const short4v*>(
                    (char*)Vt + rb + ((c0 ^ sw) * 16) + h8);
                const short4v hi = *reinterpret_cast<const short4v*>(
                    (char*)Vt + rb + (((c0 + 2) ^ sw) * 16) + h8);
                short8 vf;
                vf[0] = lo[0]; vf[1] = lo[1]; vf[2] = lo[2]; vf[3] = lo[3];
                vf[4] = hi[0]; vf[5] = hi[1]; vf[6] = hi[2]; vf[7] = hi[3];
                yacc[dt] = __builtin_amdgcn_mfma_f32_16x16x32_bf16(
                    vf, pfrag[ks2], yacc[dt], 0, 0, 0);
            }
        }
    }

    // --- epilogue: lane holds Y^T[dt*16+lh*4+i][q=lq]; scatter float4 ---
    const float inv = 1.f / lrun;
    float* orow = att + (((size_t)b * T + t0w + lq) * 16 + h) * 64;
    #pragma unroll
    for (int dt = 0; dt < 4; ++dt) {
        f32x4 o = yacc[dt] * inv;
        *reinterpret_cast<f32x4*>(orow + dt * 16 + lh * 4) = o;
    }
}

// ---------------------------------------------------------------------------
extern "C" void kernel_launch(void* const* d_in, const int* in_sizes, int n_in,
                              void* d_out, int out_size, void* d_ws, size_t ws_size,
                              hipStream_t stream) {
    const float* x    = (const float*)d_in[0];
    const float* cosb = (const float*)d_in[1];
    const float* sinb = (const float*)d_in[2];
    const float* Wq   = (const float*)d_in[3];
    const float* Wk   = (const float*)d_in[4];
    const float* Wv   = (const float*)d_in[5];
    const float* Wo   = (const float*)d_in[6];
    float* out = (float*)d_out;

    const int B = 2, T = 2048;
    const int M = B * T;   // 4096

    // workspace layout (bytes):
    //   [0,16M)   qb f32 [B,T,16,64]  -- reused as att after rope consumes it
    //   [16M,20M) kb f32 [B,T,4,64]
    //   [20M,24M) vb f32 [B,T,4,64]
    //   [24M,32M) q16 bf16 [B,16,T,64]
    //   [32M,34M) k16 bf16 [B,4,T,64]
    //   [34M,36M) vT16 bf16 [B,4,64,T]
    char* wsb = (char*)d_ws;
    float* qb  = (float*)(wsb);
    float* kb  = (float*)(wsb + (size_t)16 * 1024 * 1024);
    float* vb  = (float*)(wsb + (size_t)20 * 1024 * 1024);
    short* q16 = (short*)(wsb + (size_t)24 * 1024 * 1024);
    short* k16 = (short*)(wsb + (size_t)32 * 1024 * 1024);
    short* vT16= (short*)(wsb + (size_t)34 * 1024 * 1024);
    float* att = qb;   // safe: attn reads only q16/k16/vT16

    // QKV projections (f32)
    gemm_f32<<<dim3(1024 / 64, M / 64), 256, 0, stream>>>(x, Wq, qb, M, 1024, 1024);
    gemm_f32<<<dim3(256 / 64,  M / 64), 256, 0, stream>>>(x, Wk, kb, M, 256, 1024);
    gemm_f32<<<dim3(256 / 64,  M / 64), 256, 0, stream>>>(x, Wv, vb, M, 256, 1024);

    // RoPE + RMSNorm + cast to bf16 head-major
    rope_rmsnorm_cast<<<(B * T * 20) / 4, 256, 0, stream>>>(qb, kb, cosb, sinb,
                                                            q16, k16, B, T);
    // V cast + transpose
    vcast_transpose<<<dim3(T / 64, 4, B), 256, 0, stream>>>(vb, vT16, B, T);

    // bf16 MFMA flash attention -> att f32 [B,T,16,64]
    attn_mfma<<<dim3(T / 64, 16, B), 256, 0, stream>>>(q16, k16, vT16, att, B, T);

    // output projection (f32)
    gemm_f32<<<dim3(1024 / 64, M / 64), 256, 0, stream>>>(att, Wo, out, M, 1024, 1024);
}

// Round 3
// 173.937 us; speedup vs baseline: 11.7897x; 2.9398x over previous
//
#include <hip/hip_runtime.h>
#include <hip/hip_bf16.h>
#include <math.h>

#define EPS 1e-6f

typedef __attribute__((ext_vector_type(8))) short short8;
typedef __attribute__((ext_vector_type(4))) short short4v;
typedef __attribute__((ext_vector_type(4))) float f32x4;

// f32 -> bf16 (round-to-nearest-even)
static __device__ __forceinline__ short f2bf(float x) {
    unsigned u = __builtin_bit_cast(unsigned, x);
    u += 0x7fffu + ((u >> 16) & 1u);
    return (short)(u >> 16);
}

typedef __attribute__((address_space(1))) const void gvoid_t;
typedef __attribute__((address_space(3))) void lvoid_t;
static __device__ __forceinline__ void gload_lds16(const void* g, void* l) {
    // 16B direct global->LDS. LDS dest is wave-uniform base + lane*16 (HW).
    __builtin_amdgcn_global_load_lds((gvoid_t*)g, (lvoid_t*)l, 16, 0, 0);
}

// ---------------------------------------------------------------------------
// x f32 -> bf16, 8 elems/thread
// ---------------------------------------------------------------------------
__global__ __launch_bounds__(256) void cast_f32_bf16(const float* __restrict__ src,
                                                     short* __restrict__ dst, int n8) {
    const int i = blockIdx.x * 256 + threadIdx.x;
    if (i >= n8) return;
    const float4 a = reinterpret_cast<const float4*>(src)[2 * i];
    const float4 b = reinterpret_cast<const float4*>(src)[2 * i + 1];
    short8 o;
    o[0] = f2bf(a.x); o[1] = f2bf(a.y); o[2] = f2bf(a.z); o[3] = f2bf(a.w);
    o[4] = f2bf(b.x); o[5] = f2bf(b.y); o[6] = f2bf(b.z); o[7] = f2bf(b.w);
    reinterpret_cast<short8*>(dst)[i] = o;
}

// ---------------------------------------------------------------------------
// W f32 [K][N] row-major -> W^T bf16 [N][K] row-major (dst row stride = Kd).
// 64x64 LDS tile transpose; grid (N/64, K/64).
// ---------------------------------------------------------------------------
__global__ __launch_bounds__(256) void transpose_cast_w(const float* __restrict__ src,
                                                        short* __restrict__ dst,
                                                        int K, int N, int Kd) {
    __shared__ short tl[64][65];
    const int tid = threadIdx.x;
    const int k0 = blockIdx.y * 64, n0 = blockIdx.x * 64;

    #pragma unroll
    for (int i = 0; i < 4; ++i) {
        const int kr = (tid >> 4) + i * 16;
        const int c4 = (tid & 15) * 4;
        const float4 v = *reinterpret_cast<const float4*>(
            &src[(size_t)(k0 + kr) * N + n0 + c4]);
        tl[kr][c4 + 0] = f2bf(v.x);
        tl[kr][c4 + 1] = f2bf(v.y);
        tl[kr][c4 + 2] = f2bf(v.z);
        tl[kr][c4 + 3] = f2bf(v.w);
    }
    __syncthreads();

    const int nr  = tid >> 2;
    const int kc0 = (tid & 3) * 16;
    short tmp[16];
    #pragma unroll
    for (int j = 0; j < 16; ++j) tmp[j] = tl[kc0 + j][nr];
    short8* outp = reinterpret_cast<short8*>(&dst[(size_t)(n0 + nr) * Kd + k0 + kc0]);
    outp[0] = *reinterpret_cast<short8*>(&tmp[0]);
    outp[1] = *reinterpret_cast<short8*>(&tmp[8]);
}

// ---------------------------------------------------------------------------
// bf16 MFMA GEMM: C[M,N] f32 = A[M,K] bf16 · B^T[N,K] bf16.
// 128x128 tile, BK=32, 4 waves (2x2), 16 MFMA(16x16x32)/wave/K-step.
// global_load_lds 16B staging; XOR chunk swizzle c^((r>>1)&3) applied on the
// GLOBAL source address (LDS dest stays linear) and on the ds_read side.
// ---------------------------------------------------------------------------
__global__ __launch_bounds__(256) void gemm_bf16(const short* __restrict__ A,
                                                 const short* __restrict__ BT,
                                                 float* __restrict__ C,
                                                 int M, int N, int K) {
    __shared__ short As[2][128 * 32];
    __shared__ short Bs[2][128 * 32];

    const int tid  = threadIdx.x;
    const int lane = tid & 63;
    const int w    = tid >> 6;
    const int lq = lane & 15, lh = lane >> 4;
    const int wm = w >> 1,   wn = w & 1;
    const size_t arow0 = (size_t)blockIdx.y * 128;
    const size_t brow0 = (size_t)blockIdx.x * 128;

    f32x4 acc[4][4];
    #pragma unroll
    for (int mi = 0; mi < 4; ++mi)
        #pragma unroll
        for (int ni = 0; ni < 4; ++ni) acc[mi][ni] = (f32x4){0.f, 0.f, 0.f, 0.f};

    const int NT = K >> 5;
    int cur = 0;

    // prologue stage of tile 0
    #pragma unroll
    for (int i = 0; i < 2; ++i) {
        const int ch = w * 64 + i * 256 + lane;
        const int r = ch >> 2, c = ch & 3;
        const int cg = c ^ ((r >> 1) & 3);
        gload_lds16(A + (arow0 + r) * K + cg * 8, &As[0][(w * 64 + i * 256) * 8]);
        gload_lds16(BT + (brow0 + r) * K + cg * 8, &Bs[0][(w * 64 + i * 256) * 8]);
    }
    __syncthreads();

    for (int t = 0; t < NT; ++t) {
        if (t + 1 < NT) {
            const int k0 = (t + 1) << 5;
            #pragma unroll
            for (int i = 0; i < 2; ++i) {
                const int ch = w * 64 + i * 256 + lane;
                const int r = ch >> 2, c = ch & 3;
                const int cg = c ^ ((r >> 1) & 3);
                gload_lds16(A + (arow0 + r) * K + k0 + cg * 8,
                            &As[cur ^ 1][(w * 64 + i * 256) * 8]);
                gload_lds16(BT + (brow0 + r) * K + k0 + cg * 8,
                            &Bs[cur ^ 1][(w * 64 + i * 256) * 8]);
            }
        }

        short8 af[4], bf[4];
        #pragma unroll
        for (int mi = 0; mi < 4; ++mi) {
            const int r = wm * 64 + mi * 16 + lq;
            af[mi] = *reinterpret_cast<const short8*>(
                &As[cur][r * 32 + ((lh ^ ((r >> 1) & 3)) * 8)]);
        }
        #pragma unroll
        for (int ni = 0; ni < 4; ++ni) {
            const int r = wn * 64 + ni * 16 + lq;
            bf[ni] = *reinterpret_cast<const short8*>(
                &Bs[cur][r * 32 + ((lh ^ ((r >> 1) & 3)) * 8)]);
        }
        #pragma unroll
        for (int mi = 0; mi < 4; ++mi)
            #pragma unroll
            for (int ni = 0; ni < 4; ++ni)
                acc[mi][ni] = __builtin_amdgcn_mfma_f32_16x16x32_bf16(
                    af[mi], bf[ni], acc[mi][ni], 0, 0, 0);

        __syncthreads();   // drains vmcnt(0): next buffer staged & this buffer free
        cur ^= 1;
    }

    // epilogue: D[m=lh*4+i][n=lq] per 16x16 subtile
    #pragma unroll
    for (int mi = 0; mi < 4; ++mi) {
        const size_t row = arow0 + wm * 64 + mi * 16 + lh * 4;
        #pragma unroll
        for (int ni = 0; ni < 4; ++ni) {
            const size_t col = brow0 + wn * 64 + ni * 16 + lq;
            #pragma unroll
            for (int i = 0; i < 4; ++i)
                C[(row + i) * N + col] = acc[mi][ni][i];
        }
    }
}

// ---------------------------------------------------------------------------
// RoPE + RMSNorm on qkv f32 [B,T,1536] -> bf16 head-major.
//   q16: [B,16,T,64] (softmax scale folded), k16: [B,4,T,64]
// ---------------------------------------------------------------------------
__global__ __launch_bounds__(256) void rope_rmsnorm_cast(
    const float* __restrict__ qkv, const float* __restrict__ cosb,
    const float* __restrict__ sinb, short* __restrict__ q16,
    short* __restrict__ k16, int B, int T) {
    const int lane = threadIdx.x & 63;
    const int wid  = threadIdx.x >> 6;
    const int row  = blockIdx.x * 4 + wid;
    const int bt = row / 20;
    const int h  = row % 20;
    const int b  = bt / T, t = bt % T;

    const float* src = (h < 16) ? qkv + (size_t)bt * 1536 + h * 64
                                : qkv + (size_t)bt * 1536 + 1024 + (h - 16) * 64;

    const int j = lane & 31;
    const float x1 = src[j];
    const float x2 = src[j + 32];
    const float c = cosb[t * 32 + j];
    const float s = sinb[t * 32 + j];
    float y = (lane < 32) ? (x1 * c + x2 * s) : (x2 * c - x1 * s);

    float ss = y * y;
    #pragma unroll
    for (int m = 1; m < 64; m <<= 1) ss += __shfl_xor(ss, m);
    const float r = rsqrtf(ss * (1.0f / 64.0f) + EPS);

    if (h < 16)
        q16[((size_t)(b * 16 + h) * T + t) * 64 + lane] = f2bf(y * r * 0.125f);
    else
        k16[((size_t)(b * 4 + (h - 16)) * T + t) * 64 + lane] = f2bf(y * r);
}

// ---------------------------------------------------------------------------
// v slice of qkv (f32, stride 1536) -> bf16 transposed vT16 [B,4,64,T]
// ---------------------------------------------------------------------------
__global__ __launch_bounds__(256) void vcast_transpose(
    const float* __restrict__ qkv, short* __restrict__ vT, int B, int T) {
    __shared__ short tl[64][65];
    const int tid = threadIdx.x;
    const int b = blockIdx.z, kvh = blockIdx.y, t0 = blockIdx.x * 64;

    #pragma unroll
    for (int i = 0; i < 4; ++i) {
        const int tr = (tid >> 4) + i * 16;
        const int d4 = (tid & 15) * 4;
        const float4 v4 = *reinterpret_cast<const float4*>(
            &qkv[(size_t)(b * T + t0 + tr) * 1536 + 1280 + kvh * 64 + d4]);
        tl[tr][d4 + 0] = f2bf(v4.x);
        tl[tr][d4 + 1] = f2bf(v4.y);
        tl[tr][d4 + 2] = f2bf(v4.z);
        tl[tr][d4 + 3] = f2bf(v4.w);
    }
    __syncthreads();

    const int dim = tid >> 2;
    const int tq  = (tid & 3) * 16;
    short tmp[16];
    #pragma unroll
    for (int j2 = 0; j2 < 16; ++j2) tmp[j2] = tl[tq + j2][dim];
    short8* outp = reinterpret_cast<short8*>(
        &vT[((size_t)(b * 4 + kvh) * 64 + dim) * T + t0 + tq]);
    outp[0] = *reinterpret_cast<short8*>(&tmp[0]);
    outp[1] = *reinterpret_cast<short8*>(&tmp[8]);
}

// ---------------------------------------------------------------------------
// bf16 MFMA flash attention (causal, GQA 4:1), D=64 — round-2 kernel,
// epilogue now writes bf16 att [B,T,16,64] for the Wo GEMM.
// ---------------------------------------------------------------------------
__global__ __launch_bounds__(256) void attn_mfma(
    const short* __restrict__ q16, const short* __restrict__ k16,
    const short* __restrict__ vT16, short* __restrict__ att16, int B, int T) {
    __shared__ short Kt[64 * 64];
    __shared__ short Vt[64 * 64];

    const int tid  = threadIdx.x;
    const int lane = tid & 63;
    const int w    = tid >> 6;
    const int lq   = lane & 15;
    const int lh   = lane >> 4;
    const int qb = blockIdx.x, h = blockIdx.y, b = blockIdx.z;
    const int hk = h >> 2;
    const int t0w = qb * 64 + w * 16;

    const short* qrow = q16 + ((size_t)(b * 16 + h) * T + t0w + lq) * 64;
    const short8 qf0 = *reinterpret_cast<const short8*>(qrow + lh * 8);
    const short8 qf1 = *reinterpret_cast<const short8*>(qrow + 32 + lh * 8);

    const short* kgbase = k16 + (size_t)(b * 4 + hk) * T * 64;
    const short* vgbase = vT16 + (size_t)(b * 4 + hk) * 64 * T;

    f32x4 yacc[4];
    #pragma unroll
    for (int dt = 0; dt < 4; ++dt) yacc[dt] = (f32x4){0.f, 0.f, 0.f, 0.f};
    float mrun = -1e30f, lrun = 0.f;

    for (int ti = 0; ti <= qb; ++ti) {
        const int s0 = ti * 64;
        __syncthreads();
        #pragma unroll
        for (int i = 0; i < 2; ++i) {
            const int cid = tid + i * 256;
            const int r = cid >> 3, c = cid & 7;
            const short8 kv = *reinterpret_cast<const short8*>(
                kgbase + (size_t)(s0 + r) * 64 + c * 8);
            *reinterpret_cast<short8*>(
                (char*)Kt + r * 128 + ((c ^ (r & 7)) * 16)) = kv;
            const short8 vv = *reinterpret_cast<const short8*>(
                vgbase + (size_t)r * T + s0 + c * 8);
            *reinterpret_cast<short8*>(
                (char*)Vt + r * 128 + ((c ^ (r & 7)) * 16)) = vv;
        }
        __syncthreads();

        f32x4 st[4];
        #pragma unroll
        for (int ks = 0; ks < 4; ++ks) {
            f32x4 acc = (f32x4){0.f, 0.f, 0.f, 0.f};
            #pragma unroll
            for (int dk = 0; dk < 2; ++dk) {
                const short8 kfr = *reinterpret_cast<const short8*>(
                    (char*)Kt + (ks * 16 + lq) * 128 +
                    (((dk * 4 + lh) ^ (lq & 7)) * 16));
                acc = __builtin_amdgcn_mfma_f32_16x16x32_bf16(
                    kfr, dk ? qf1 : qf0, acc, 0, 0, 0);
            }
            st[ks] = acc;
        }

        if (ti == qb) {
            #pragma unroll
            for (int ks = 0; ks < 4; ++ks)
                #pragma unroll
                for (int i2 = 0; i2 < 4; ++i2)
                    if (ks * 16 + lh * 4 + i2 > w * 16 + lq)
                        st[ks][i2] = -1e30f;
        }

        float pm = -1e30f;
        #pragma unroll
        for (int ks = 0; ks < 4; ++ks)
            #pragma unroll
            for (int i2 = 0; i2 < 4; ++i2) pm = fmaxf(pm, st[ks][i2]);
        pm = fmaxf(pm, __shfl_xor(pm, 16));
        pm = fmaxf(pm, __shfl_xor(pm, 32));
        const float mn  = fmaxf(mrun, pm);
        const float fsc = __expf(mrun - mn);
        float ps = 0.f;
        #pragma unroll
        for (int ks = 0; ks < 4; ++ks)
            #pragma unroll
            for (int i2 = 0; i2 < 4; ++i2) {
                const float p = __expf(st[ks][i2] - mn);
                st[ks][i2] = p;
                ps += p;
            }
        ps += __shfl_xor(ps, 16);
        ps += __shfl_xor(ps, 32);
        lrun = lrun * fsc + ps;
        mrun = mn;
        #pragma unroll
        for (int dt = 0; dt < 4; ++dt) yacc[dt] *= fsc;

        short8 pfrag[2];
        #pragma unroll
        for (int ks2 = 0; ks2 < 2; ++ks2) {
            short8 pb;
            pb[0] = f2bf(st[2 * ks2][0]);
            pb[1] = f2bf(st[2 * ks2][1]);
            pb[2] = f2bf(st[2 * ks2][2]);
            pb[3] = f2bf(st[2 * ks2][3]);
            pb[4] = f2bf(st[2 * ks2 + 1][0]);
            pb[5] = f2bf(st[2 * ks2 + 1][1]);
            pb[6] = f2bf(st[2 * ks2 + 1][2]);
            pb[7] = f2bf(st[2 * ks2 + 1][3]);
            pfrag[ks2] = pb;
        }

        #pragma unroll
        for (int dt = 0; dt < 4; ++dt) {
            const int rb = (dt * 16 + lq) * 128;
            const int sw = lq & 7;
            #pragma unroll
            for (int ks2 = 0; ks2 < 2; ++ks2) {
                const int c0 = ks2 * 4 + (lh >> 1);
                const int h8 = (lh & 1) * 8;
                const short4v lo = *reinterpret_cast<const short4v*>(
                    (char*)Vt + rb + ((c0 ^ sw) * 16) + h8);
                const short4v hi = *reinterpret_cast<const short4v*>(
                    (char*)Vt + rb + (((c0 + 2) ^ sw) * 16) + h8);
                short8 vf;
                vf[0] = lo[0]; vf[1] = lo[1]; vf[2] = lo[2]; vf[3] = lo[3];
                vf[4] = hi[0]; vf[5] = hi[1]; vf[6] = hi[2]; vf[7] = hi[3];
                yacc[dt] = __builtin_amdgcn_mfma_f32_16x16x32_bf16(
                    vf, pfrag[ks2], yacc[dt], 0, 0, 0);
            }
        }
    }

    const float inv = 1.f / lrun;
    short* orow = att16 + (((size_t)b * T + t0w + lq) * 16 + h) * 64;
    #pragma unroll
    for (int dt = 0; dt < 4; ++dt) {
        short4v o;
        o[0] = f2bf(yacc[dt][0] * inv);
        o[1] = f2bf(yacc[dt][1] * inv);
        o[2] = f2bf(yacc[dt][2] * inv);
        o[3] = f2bf(yacc[dt][3] * inv);
        *reinterpret_cast<short4v*>(orow + dt * 16 + lh * 4) = o;
    }
}

// ---------------------------------------------------------------------------
extern "C" void kernel_launch(void* const* d_in, const int* in_sizes, int n_in,
                              void* d_out, int out_size, void* d_ws, size_t ws_size,
                              hipStream_t stream) {
    const float* x    = (const float*)d_in[0];
    const float* cosb = (const float*)d_in[1];
    const float* sinb = (const float*)d_in[2];
    const float* Wq   = (const float*)d_in[3];
    const float* Wk   = (const float*)d_in[4];
    const float* Wv   = (const float*)d_in[5];
    const float* Wo   = (const float*)d_in[6];
    float* out = (float*)d_out;

    const int B = 2, T = 2048;
    const int M = B * T;   // 4096
    const size_t MB = 1 << 20;

    // workspace (38 MB):
    //  [0,24M)  qkv f32 [4096][1536]; att16 bf16 [4096][1024] overlays [0,8M)
    //  [24,32M) x16 bf16 [4096][1024]; q16 overlays after QKV GEMM
    //  [32,35M) WT bf16 [1536][1024]; k16 overlays [32,34M) after QKV GEMM
    //  [34,36M) vT16 bf16 [B,4,64,T] (overlays WT tail after QKV GEMM)
    //  [36,38M) WoT bf16 [1024][1024]
    char* wsb = (char*)d_ws;
    float* qkv  = (float*)(wsb);
    short* att16= (short*)(wsb);
    short* x16  = (short*)(wsb + 24 * MB);
    short* q16  = (short*)(wsb + 24 * MB);
    short* WT   = (short*)(wsb + 32 * MB);
    short* k16  = (short*)(wsb + 32 * MB);
    short* vT16 = (short*)(wsb + 34 * MB);
    short* WoT  = (short*)(wsb + 36 * MB);

    // casts / transposes
    cast_f32_bf16<<<(M * 1024 / 8 + 255) / 256, 256, 0, stream>>>(x, x16, M * 1024 / 8);
    transpose_cast_w<<<dim3(16, 16), 256, 0, stream>>>(Wq, WT,                 1024, 1024, 1024);
    transpose_cast_w<<<dim3(4, 16),  256, 0, stream>>>(Wk, WT + 1024 * 1024,   1024, 256,  1024);
    transpose_cast_w<<<dim3(4, 16),  256, 0, stream>>>(Wv, WT + 1280 * 1024,   1024, 256,  1024);
    transpose_cast_w<<<dim3(16, 16), 256, 0, stream>>>(Wo, WoT,                1024, 1024, 1024);

    // fused QKV projection: [4096,1024] x [1536,1024]^T -> [4096,1536] f32
    gemm_bf16<<<dim3(1536 / 128, M / 128), 256, 0, stream>>>(x16, WT, qkv, M, 1536, 1024);

    // RoPE + RMSNorm + cast (q,k) ; V cast+transpose
    rope_rmsnorm_cast<<<(B * T * 20) / 4, 256, 0, stream>>>(qkv, cosb, sinb, q16, k16, B, T);
    vcast_transpose<<<dim3(T / 64, 4, B), 256, 0, stream>>>(qkv, vT16, B, T);

    // flash attention -> att16 bf16 [B,T,16,64]
    attn_mfma<<<dim3(T / 64, 16, B), 256, 0, stream>>>(q16, k16, vT16, att16, B, T);

    // output projection: [4096,1024] x [1024,1024]^T -> out f32
    gemm_bf16<<<dim3(1024 / 128, M / 128), 256, 0, stream>>>(att16, WoT, out, M, 1024, 1024);
}

// Round 4
// 147.383 us; speedup vs baseline: 13.9138x; 1.1802x over previous
//
#include <hip/hip_runtime.h>
#include <hip/hip_bf16.h>
#include <math.h>

#define EPS 1e-6f
#define LOG2E 1.44269504088896340736f

typedef __attribute__((ext_vector_type(8))) short short8;
typedef __attribute__((ext_vector_type(4))) short short4v;
typedef __attribute__((ext_vector_type(4))) float f32x4;

// f32 -> bf16 (round-to-nearest-even)
static __device__ __forceinline__ short f2bf(float x) {
    unsigned u = __builtin_bit_cast(unsigned, x);
    u += 0x7fffu + ((u >> 16) & 1u);
    return (short)(u >> 16);
}

typedef __attribute__((address_space(1))) const void gvoid_t;
typedef __attribute__((address_space(3))) void lvoid_t;
static __device__ __forceinline__ void gload_lds16(const void* g, void* l) {
    __builtin_amdgcn_global_load_lds((gvoid_t*)g, (lvoid_t*)l, 16, 0, 0);
}

// ---------------------------------------------------------------------------
// x f32 -> bf16, 8 elems/thread
// ---------------------------------------------------------------------------
__global__ __launch_bounds__(256) void cast_f32_bf16(const float* __restrict__ src,
                                                     short* __restrict__ dst, int n8) {
    const int i = blockIdx.x * 256 + threadIdx.x;
    if (i >= n8) return;
    const float4 a = reinterpret_cast<const float4*>(src)[2 * i];
    const float4 b = reinterpret_cast<const float4*>(src)[2 * i + 1];
    short8 o;
    o[0] = f2bf(a.x); o[1] = f2bf(a.y); o[2] = f2bf(a.z); o[3] = f2bf(a.w);
    o[4] = f2bf(b.x); o[5] = f2bf(b.y); o[6] = f2bf(b.z); o[7] = f2bf(b.w);
    reinterpret_cast<short8*>(dst)[i] = o;
}

// ---------------------------------------------------------------------------
// W f32 [K][N] row-major -> W^T bf16 [N][K] row-major (dst row stride = Kd).
// ---------------------------------------------------------------------------
__global__ __launch_bounds__(256) void transpose_cast_w(const float* __restrict__ src,
                                                        short* __restrict__ dst,
                                                        int K, int N, int Kd) {
    __shared__ short tl[64][65];
    const int tid = threadIdx.x;
    const int k0 = blockIdx.y * 64, n0 = blockIdx.x * 64;

    #pragma unroll
    for (int i = 0; i < 4; ++i) {
        const int kr = (tid >> 4) + i * 16;
        const int c4 = (tid & 15) * 4;
        const float4 v = *reinterpret_cast<const float4*>(
            &src[(size_t)(k0 + kr) * N + n0 + c4]);
        tl[kr][c4 + 0] = f2bf(v.x);
        tl[kr][c4 + 1] = f2bf(v.y);
        tl[kr][c4 + 2] = f2bf(v.z);
        tl[kr][c4 + 3] = f2bf(v.w);
    }
    __syncthreads();

    const int nr  = tid >> 2;
    const int kc0 = (tid & 3) * 16;
    short tmp[16];
    #pragma unroll
    for (int j = 0; j < 16; ++j) tmp[j] = tl[kc0 + j][nr];
    short8* outp = reinterpret_cast<short8*>(&dst[(size_t)(n0 + nr) * Kd + k0 + kc0]);
    outp[0] = *reinterpret_cast<short8*>(&tmp[0]);
    outp[1] = *reinterpret_cast<short8*>(&tmp[8]);
}

// ---------------------------------------------------------------------------
// bf16 MFMA GEMM: C[M,N] f32 = A[M,K] bf16 · B^T[N,K] bf16.  (unchanged)
// ---------------------------------------------------------------------------
__global__ __launch_bounds__(256) void gemm_bf16(const short* __restrict__ A,
                                                 const short* __restrict__ BT,
                                                 float* __restrict__ C,
                                                 int M, int N, int K) {
    __shared__ short As[2][128 * 32];
    __shared__ short Bs[2][128 * 32];

    const int tid  = threadIdx.x;
    const int lane = tid & 63;
    const int w    = tid >> 6;
    const int lq = lane & 15, lh = lane >> 4;
    const int wm = w >> 1,   wn = w & 1;
    const size_t arow0 = (size_t)blockIdx.y * 128;
    const size_t brow0 = (size_t)blockIdx.x * 128;

    f32x4 acc[4][4];
    #pragma unroll
    for (int mi = 0; mi < 4; ++mi)
        #pragma unroll
        for (int ni = 0; ni < 4; ++ni) acc[mi][ni] = (f32x4){0.f, 0.f, 0.f, 0.f};

    const int NT = K >> 5;
    int cur = 0;

    #pragma unroll
    for (int i = 0; i < 2; ++i) {
        const int ch = w * 64 + i * 256 + lane;
        const int r = ch >> 2, c = ch & 3;
        const int cg = c ^ ((r >> 1) & 3);
        gload_lds16(A + (arow0 + r) * K + cg * 8, &As[0][(w * 64 + i * 256) * 8]);
        gload_lds16(BT + (brow0 + r) * K + cg * 8, &Bs[0][(w * 64 + i * 256) * 8]);
    }
    __syncthreads();

    for (int t = 0; t < NT; ++t) {
        if (t + 1 < NT) {
            const int k0 = (t + 1) << 5;
            #pragma unroll
            for (int i = 0; i < 2; ++i) {
                const int ch = w * 64 + i * 256 + lane;
                const int r = ch >> 2, c = ch & 3;
                const int cg = c ^ ((r >> 1) & 3);
                gload_lds16(A + (arow0 + r) * K + k0 + cg * 8,
                            &As[cur ^ 1][(w * 64 + i * 256) * 8]);
                gload_lds16(BT + (brow0 + r) * K + k0 + cg * 8,
                            &Bs[cur ^ 1][(w * 64 + i * 256) * 8]);
            }
        }

        short8 af[4], bf[4];
        #pragma unroll
        for (int mi = 0; mi < 4; ++mi) {
            const int r = wm * 64 + mi * 16 + lq;
            af[mi] = *reinterpret_cast<const short8*>(
                &As[cur][r * 32 + ((lh ^ ((r >> 1) & 3)) * 8)]);
        }
        #pragma unroll
        for (int ni = 0; ni < 4; ++ni) {
            const int r = wn * 64 + ni * 16 + lq;
            bf[ni] = *reinterpret_cast<const short8*>(
                &Bs[cur][r * 32 + ((lh ^ ((r >> 1) & 3)) * 8)]);
        }
        #pragma unroll
        for (int mi = 0; mi < 4; ++mi)
            #pragma unroll
            for (int ni = 0; ni < 4; ++ni)
                acc[mi][ni] = __builtin_amdgcn_mfma_f32_16x16x32_bf16(
                    af[mi], bf[ni], acc[mi][ni], 0, 0, 0);

        __syncthreads();
        cur ^= 1;
    }

    #pragma unroll
    for (int mi = 0; mi < 4; ++mi) {
        const size_t row = arow0 + wm * 64 + mi * 16 + lh * 4;
        #pragma unroll
        for (int ni = 0; ni < 4; ++ni) {
            const size_t col = brow0 + wn * 64 + ni * 16 + lq;
            #pragma unroll
            for (int i = 0; i < 4; ++i)
                C[(row + i) * N + col] = acc[mi][ni][i];
        }
    }
}

// ---------------------------------------------------------------------------
// RoPE + RMSNorm on qkv f32 [B,T,1536] -> bf16 head-major.
//   q16: [B,16,T,64] (0.125*log2e folded -> attention uses exp2)
//   k16: [B, 4,T,64]
// ---------------------------------------------------------------------------
__global__ __launch_bounds__(256) void rope_rmsnorm_cast(
    const float* __restrict__ qkv, const float* __restrict__ cosb,
    const float* __restrict__ sinb, short* __restrict__ q16,
    short* __restrict__ k16, int B, int T) {
    const int lane = threadIdx.x & 63;
    const int wid  = threadIdx.x >> 6;
    const int row  = blockIdx.x * 4 + wid;
    const int bt = row / 20;
    const int h  = row % 20;
    const int b  = bt / T, t = bt % T;

    const float* src = (h < 16) ? qkv + (size_t)bt * 1536 + h * 64
                                : qkv + (size_t)bt * 1536 + 1024 + (h - 16) * 64;

    const int j = lane & 31;
    const float x1 = src[j];
    const float x2 = src[j + 32];
    const float c = cosb[t * 32 + j];
    const float s = sinb[t * 32 + j];
    float y = (lane < 32) ? (x1 * c + x2 * s) : (x2 * c - x1 * s);

    float ss = y * y;
    #pragma unroll
    for (int m = 1; m < 64; m <<= 1) ss += __shfl_xor(ss, m);
    const float r = rsqrtf(ss * (1.0f / 64.0f) + EPS);

    if (h < 16)
        q16[((size_t)(b * 16 + h) * T + t) * 64 + lane] = f2bf(y * r * (0.125f * LOG2E));
    else
        k16[((size_t)(b * 4 + (h - 16)) * T + t) * 64 + lane] = f2bf(y * r);
}

// ---------------------------------------------------------------------------
// v slice of qkv (f32, stride 1536) -> bf16 transposed vT16 [B,4,64,T]
// ---------------------------------------------------------------------------
__global__ __launch_bounds__(256) void vcast_transpose(
    const float* __restrict__ qkv, short* __restrict__ vT, int B, int T) {
    __shared__ short tl[64][65];
    const int tid = threadIdx.x;
    const int b = blockIdx.z, kvh = blockIdx.y, t0 = blockIdx.x * 64;

    #pragma unroll
    for (int i = 0; i < 4; ++i) {
        const int tr = (tid >> 4) + i * 16;
        const int d4 = (tid & 15) * 4;
        const float4 v4 = *reinterpret_cast<const float4*>(
            &qkv[(size_t)(b * T + t0 + tr) * 1536 + 1280 + kvh * 64 + d4]);
        tl[tr][d4 + 0] = f2bf(v4.x);
        tl[tr][d4 + 1] = f2bf(v4.y);
        tl[tr][d4 + 2] = f2bf(v4.z);
        tl[tr][d4 + 3] = f2bf(v4.w);
    }
    __syncthreads();

    const int dim = tid >> 2;
    const int tq  = (tid & 3) * 16;
    short tmp[16];
    #pragma unroll
    for (int j2 = 0; j2 < 16; ++j2) tmp[j2] = tl[tq + j2][dim];
    short8* outp = reinterpret_cast<short8*>(
        &vT[((size_t)(b * 4 + kvh) * 64 + dim) * T + t0 + tq]);
    outp[0] = *reinterpret_cast<short8*>(&tmp[0]);
    outp[1] = *reinterpret_cast<short8*>(&tmp[8]);
}

// ---------------------------------------------------------------------------
// softmax (exp2 units, defer-max) + PV for one 64-key tile of one q-tile.
// st: S^T scores (log2 units). yacc: Y^T accum. Vt: swizzled V^T LDS tile.
// ---------------------------------------------------------------------------
static __device__ __forceinline__ void sm_pv(f32x4 (&st)[4], f32x4 (&yacc)[4],
                                             float& mrun, float& lrun,
                                             const short* Vt,
                                             const int lq, const int lh) {
    float pm = -1e30f;
    #pragma unroll
    for (int ks = 0; ks < 4; ++ks)
        #pragma unroll
        for (int i2 = 0; i2 < 4; ++i2) pm = fmaxf(pm, st[ks][i2]);
    pm = fmaxf(pm, __shfl_xor(pm, 16));
    pm = fmaxf(pm, __shfl_xor(pm, 32));

    // defer-max (T13): skip yacc rescale while max growth <= 8 (log2 units)
    if (!__all(pm - mrun <= 8.0f)) {
        const float mn  = fmaxf(mrun, pm);
        const float fsc = exp2f(mrun - mn);
        #pragma unroll
        for (int dt = 0; dt < 4; ++dt) yacc[dt] *= fsc;
        lrun *= fsc;
        mrun = mn;
    }

    float ps = 0.f;
    #pragma unroll
    for (int ks = 0; ks < 4; ++ks)
        #pragma unroll
        for (int i2 = 0; i2 < 4; ++i2) {
            const float pv = exp2f(st[ks][i2] - mrun);
            st[ks][i2] = pv;
            ps += pv;
        }
    ps += __shfl_xor(ps, 16);
    ps += __shfl_xor(ps, 32);
    lrun += ps;

    short8 pfrag[2];
    #pragma unroll
    for (int ks2 = 0; ks2 < 2; ++ks2) {
        short8 pb;
        pb[0] = f2bf(st[2 * ks2][0]);
        pb[1] = f2bf(st[2 * ks2][1]);
        pb[2] = f2bf(st[2 * ks2][2]);
        pb[3] = f2bf(st[2 * ks2][3]);
        pb[4] = f2bf(st[2 * ks2 + 1][0]);
        pb[5] = f2bf(st[2 * ks2 + 1][1]);
        pb[6] = f2bf(st[2 * ks2 + 1][2]);
        pb[7] = f2bf(st[2 * ks2 + 1][3]);
        pfrag[ks2] = pb;
    }

    __builtin_amdgcn_s_setprio(1);
    #pragma unroll
    for (int dt = 0; dt < 4; ++dt) {
        const int rb = (dt * 16 + lq) * 128;
        const int sw = lq & 7;
        #pragma unroll
        for (int ks2 = 0; ks2 < 2; ++ks2) {
            const int c0 = ks2 * 4 + (lh >> 1);
            const int h8 = (lh & 1) * 8;
            const short4v lo = *reinterpret_cast<const short4v*>(
                (const char*)Vt + rb + ((c0 ^ sw) * 16) + h8);
            const short4v hi = *reinterpret_cast<const short4v*>(
                (const char*)Vt + rb + (((c0 + 2) ^ sw) * 16) + h8);
            short8 vf;
            vf[0] = lo[0]; vf[1] = lo[1]; vf[2] = lo[2]; vf[3] = lo[3];
            vf[4] = hi[0]; vf[5] = hi[1]; vf[6] = hi[2]; vf[7] = hi[3];
            yacc[dt] = __builtin_amdgcn_mfma_f32_16x16x32_bf16(
                vf, pfrag[ks2], yacc[dt], 0, 0, 0);
        }
    }
    __builtin_amdgcn_s_setprio(0);
}

// ---------------------------------------------------------------------------
// bf16 MFMA flash attention, paired q-tiles for causal load balance.
// Block p handles q-tiles qb_lo=p and qb_hi=nqb-1-p of one (b,h): shared KV
// staging, uniform 33 tile-computes per block. 4 waves x 16 q-rows per tile.
// ---------------------------------------------------------------------------
__global__ __launch_bounds__(256) void attn_mfma(
    const short* __restrict__ q16, const short* __restrict__ k16,
    const short* __restrict__ vT16, short* __restrict__ att16, int B, int T) {
    __shared__ short Kt[64 * 64];
    __shared__ short Vt[64 * 64];

    const int tid  = threadIdx.x;
    const int lane = tid & 63;
    const int w    = tid >> 6;
    const int lq   = lane & 15;
    const int lh   = lane >> 4;
    const int p = blockIdx.x, h = blockIdx.y, b = blockIdx.z;
    const int hk = h >> 2;
    const int nqb = T >> 6;
    const int qb_lo = p, qb_hi = nqb - 1 - p;
    const int tlo = qb_lo * 64 + w * 16;
    const int thi = qb_hi * 64 + w * 16;

    const short* qbase = q16 + (size_t)(b * 16 + h) * T * 64;
    const short8 qlo0 = *reinterpret_cast<const short8*>(qbase + (tlo + lq) * 64 + lh * 8);
    const short8 qlo1 = *reinterpret_cast<const short8*>(qbase + (tlo + lq) * 64 + 32 + lh * 8);
    const short8 qhi0 = *reinterpret_cast<const short8*>(qbase + (thi + lq) * 64 + lh * 8);
    const short8 qhi1 = *reinterpret_cast<const short8*>(qbase + (thi + lq) * 64 + 32 + lh * 8);

    const short* kgbase = k16 + (size_t)(b * 4 + hk) * T * 64;
    const short* vgbase = vT16 + (size_t)(b * 4 + hk) * 64 * T;

    f32x4 ylo[4], yhi[4];
    #pragma unroll
    for (int dt = 0; dt < 4; ++dt) {
        ylo[dt] = (f32x4){0.f, 0.f, 0.f, 0.f};
        yhi[dt] = (f32x4){0.f, 0.f, 0.f, 0.f};
    }
    float mlo = -1e30f, llo = 0.f, mhi = -1e30f, lhi = 0.f;

    for (int ti = 0; ti <= qb_hi; ++ti) {
        const int s0 = ti * 64;
        const bool lo_act = (ti <= qb_lo);   // block-uniform
        __syncthreads();
        #pragma unroll
        for (int i = 0; i < 2; ++i) {
            const int cid = tid + i * 256;
            const int r = cid >> 3, c = cid & 7;
            const short8 kv = *reinterpret_cast<const short8*>(
                kgbase + (size_t)(s0 + r) * 64 + c * 8);
            *reinterpret_cast<short8*>(
                (char*)Kt + r * 128 + ((c ^ (r & 7)) * 16)) = kv;
            const short8 vv = *reinterpret_cast<const short8*>(
                vgbase + (size_t)r * T + s0 + c * 8);
            *reinterpret_cast<short8*>(
                (char*)Vt + r * 128 + ((c ^ (r & 7)) * 16)) = vv;
        }
        __syncthreads();

        // --- QK^T for hi (and lo if active): S^T[key][q] ---
        f32x4 shi[4], slo[4];
        __builtin_amdgcn_s_setprio(1);
        #pragma unroll
        for (int ks = 0; ks < 4; ++ks) {
            f32x4 a1 = (f32x4){0.f, 0.f, 0.f, 0.f};
            #pragma unroll
            for (int dk = 0; dk < 2; ++dk) {
                const short8 kfr = *reinterpret_cast<const short8*>(
                    (char*)Kt + (ks * 16 + lq) * 128 +
                    (((dk * 4 + lh) ^ (lq & 7)) * 16));
                a1 = __builtin_amdgcn_mfma_f32_16x16x32_bf16(
                    kfr, dk ? qhi1 : qhi0, a1, 0, 0, 0);
            }
            shi[ks] = a1;
        }
        if (lo_act) {
            #pragma unroll
            for (int ks = 0; ks < 4; ++ks) {
                f32x4 a1 = (f32x4){0.f, 0.f, 0.f, 0.f};
                #pragma unroll
                for (int dk = 0; dk < 2; ++dk) {
                    const short8 kfr = *reinterpret_cast<const short8*>(
                        (char*)Kt + (ks * 16 + lq) * 128 +
                        (((dk * 4 + lh) ^ (lq & 7)) * 16));
                    a1 = __builtin_amdgcn_mfma_f32_16x16x32_bf16(
                        kfr, dk ? qlo1 : qlo0, a1, 0, 0, 0);
                }
                slo[ks] = a1;
            }
        }
        __builtin_amdgcn_s_setprio(0);

        // --- causal masks on diagonal tiles ---
        if (ti == qb_hi) {
            #pragma unroll
            for (int ks = 0; ks < 4; ++ks)
                #pragma unroll
                for (int i2 = 0; i2 < 4; ++i2)
                    if (ks * 16 + lh * 4 + i2 > w * 16 + lq)
                        shi[ks][i2] = -1e30f;
        }
        sm_pv(shi, yhi, mhi, lhi, Vt, lq, lh);

        if (lo_act) {
            if (ti == qb_lo) {
                #pragma unroll
                for (int ks = 0; ks < 4; ++ks)
                    #pragma unroll
                    for (int i2 = 0; i2 < 4; ++i2)
                        if (ks * 16 + lh * 4 + i2 > w * 16 + lq)
                            slo[ks][i2] = -1e30f;
            }
            sm_pv(slo, ylo, mlo, llo, Vt, lq, lh);
        }
    }

    // --- epilogues ---
    const float invh = 1.f / lhi;
    short* orowh = att16 + (((size_t)b * T + thi + lq) * 16 + h) * 64;
    #pragma unroll
    for (int dt = 0; dt < 4; ++dt) {
        short4v o;
        o[0] = f2bf(yhi[dt][0] * invh);
        o[1] = f2bf(yhi[dt][1] * invh);
        o[2] = f2bf(yhi[dt][2] * invh);
        o[3] = f2bf(yhi[dt][3] * invh);
        *reinterpret_cast<short4v*>(orowh + dt * 16 + lh * 4) = o;
    }
    const float invl = 1.f / llo;
    short* orowl = att16 + (((size_t)b * T + tlo + lq) * 16 + h) * 64;
    #pragma unroll
    for (int dt = 0; dt < 4; ++dt) {
        short4v o;
        o[0] = f2bf(ylo[dt][0] * invl);
        o[1] = f2bf(ylo[dt][1] * invl);
        o[2] = f2bf(ylo[dt][2] * invl);
        o[3] = f2bf(ylo[dt][3] * invl);
        *reinterpret_cast<short4v*>(orowl + dt * 16 + lh * 4) = o;
    }
}

// ---------------------------------------------------------------------------
extern "C" void kernel_launch(void* const* d_in, const int* in_sizes, int n_in,
                              void* d_out, int out_size, void* d_ws, size_t ws_size,
                              hipStream_t stream) {
    const float* x    = (const float*)d_in[0];
    const float* cosb = (const float*)d_in[1];
    const float* sinb = (const float*)d_in[2];
    const float* Wq   = (const float*)d_in[3];
    const float* Wk   = (const float*)d_in[4];
    const float* Wv   = (const float*)d_in[5];
    const float* Wo   = (const float*)d_in[6];
    float* out = (float*)d_out;

    const int B = 2, T = 2048;
    const int M = B * T;   // 4096
    const size_t MB = 1 << 20;

    char* wsb = (char*)d_ws;
    float* qkv  = (float*)(wsb);
    short* att16= (short*)(wsb);
    short* x16  = (short*)(wsb + 24 * MB);
    short* q16  = (short*)(wsb + 24 * MB);
    short* WT   = (short*)(wsb + 32 * MB);
    short* k16  = (short*)(wsb + 32 * MB);
    short* vT16 = (short*)(wsb + 34 * MB);
    short* WoT  = (short*)(wsb + 36 * MB);

    cast_f32_bf16<<<(M * 1024 / 8 + 255) / 256, 256, 0, stream>>>(x, x16, M * 1024 / 8);
    transpose_cast_w<<<dim3(16, 16), 256, 0, stream>>>(Wq, WT,               1024, 1024, 1024);
    transpose_cast_w<<<dim3(4, 16),  256, 0, stream>>>(Wk, WT + 1024 * 1024, 1024, 256,  1024);
    transpose_cast_w<<<dim3(4, 16),  256, 0, stream>>>(Wv, WT + 1280 * 1024, 1024, 256,  1024);
    transpose_cast_w<<<dim3(16, 16), 256, 0, stream>>>(Wo, WoT,              1024, 1024, 1024);

    gemm_bf16<<<dim3(1536 / 128, M / 128), 256, 0, stream>>>(x16, WT, qkv, M, 1536, 1024);

    rope_rmsnorm_cast<<<(B * T * 20) / 4, 256, 0, stream>>>(qkv, cosb, sinb, q16, k16, B, T);
    vcast_transpose<<<dim3(T / 64, 4, B), 256, 0, stream>>>(qkv, vT16, B, T);

    // paired causal flash attention: grid.x = nqb/2 = 16
    attn_mfma<<<dim3(T / 128, 16, B), 256, 0, stream>>>(q16, k16, vT16, att16, B, T);

    gemm_bf16<<<dim3(1024 / 128, M / 128), 256, 0, stream>>>(att16, WoT, out, M, 1024, 1024);
}

// Round 5
// 139.007 us; speedup vs baseline: 14.7522x; 1.0603x over previous
//
#include <hip/hip_runtime.h>
#include <hip/hip_bf16.h>
#include <math.h>

#define EPS 1e-6f
#define LOG2E 1.44269504088896340736f

typedef __attribute__((ext_vector_type(8))) short short8;
typedef __attribute__((ext_vector_type(4))) short short4v;
typedef __attribute__((ext_vector_type(4))) float f32x4;

// f32 -> bf16 (round-to-nearest-even)
static __device__ __forceinline__ short f2bf(float x) {
    unsigned u = __builtin_bit_cast(unsigned, x);
    u += 0x7fffu + ((u >> 16) & 1u);
    return (short)(u >> 16);
}

typedef __attribute__((address_space(1))) const void gvoid_t;
typedef __attribute__((address_space(3))) void lvoid_t;
static __device__ __forceinline__ void gload_lds16(const void* g, void* l) {
    __builtin_amdgcn_global_load_lds((gvoid_t*)g, (lvoid_t*)l, 16, 0, 0);
}

// ---------------------------------------------------------------------------
// x f32 -> bf16, 8 elems/thread
// ---------------------------------------------------------------------------
__global__ __launch_bounds__(256) void cast_f32_bf16(const float* __restrict__ src,
                                                     short* __restrict__ dst, int n8) {
    const int i = blockIdx.x * 256 + threadIdx.x;
    if (i >= n8) return;
    const float4 a = reinterpret_cast<const float4*>(src)[2 * i];
    const float4 b = reinterpret_cast<const float4*>(src)[2 * i + 1];
    short8 o;
    o[0] = f2bf(a.x); o[1] = f2bf(a.y); o[2] = f2bf(a.z); o[3] = f2bf(a.w);
    o[4] = f2bf(b.x); o[5] = f2bf(b.y); o[6] = f2bf(b.z); o[7] = f2bf(b.w);
    reinterpret_cast<short8*>(dst)[i] = o;
}

// ---------------------------------------------------------------------------
// W f32 [K][N] row-major -> W^T bf16 [N][K] row-major (dst row stride = Kd).
// ---------------------------------------------------------------------------
__global__ __launch_bounds__(256) void transpose_cast_w(const float* __restrict__ src,
                                                        short* __restrict__ dst,
                                                        int K, int N, int Kd) {
    __shared__ short tl[64][65];
    const int tid = threadIdx.x;
    const int k0 = blockIdx.y * 64, n0 = blockIdx.x * 64;

    #pragma unroll
    for (int i = 0; i < 4; ++i) {
        const int kr = (tid >> 4) + i * 16;
        const int c4 = (tid & 15) * 4;
        const float4 v = *reinterpret_cast<const float4*>(
            &src[(size_t)(k0 + kr) * N + n0 + c4]);
        tl[kr][c4 + 0] = f2bf(v.x);
        tl[kr][c4 + 1] = f2bf(v.y);
        tl[kr][c4 + 2] = f2bf(v.z);
        tl[kr][c4 + 3] = f2bf(v.w);
    }
    __syncthreads();

    const int nr  = tid >> 2;
    const int kc0 = (tid & 3) * 16;
    short tmp[16];
    #pragma unroll
    for (int j = 0; j < 16; ++j) tmp[j] = tl[kc0 + j][nr];
    short8* outp = reinterpret_cast<short8*>(&dst[(size_t)(n0 + nr) * Kd + k0 + kc0]);
    outp[0] = *reinterpret_cast<short8*>(&tmp[0]);
    outp[1] = *reinterpret_cast<short8*>(&tmp[8]);
}

// ---------------------------------------------------------------------------
// bf16 MFMA GEMM: C[M,N] f32 = A[M,K] bf16 · B^T[N,K] bf16.  (unchanged)
// ---------------------------------------------------------------------------
__global__ __launch_bounds__(256) void gemm_bf16(const short* __restrict__ A,
                                                 const short* __restrict__ BT,
                                                 float* __restrict__ C,
                                                 int M, int N, int K) {
    __shared__ short As[2][128 * 32];
    __shared__ short Bs[2][128 * 32];

    const int tid  = threadIdx.x;
    const int lane = tid & 63;
    const int w    = tid >> 6;
    const int lq = lane & 15, lh = lane >> 4;
    const int wm = w >> 1,   wn = w & 1;
    const size_t arow0 = (size_t)blockIdx.y * 128;
    const size_t brow0 = (size_t)blockIdx.x * 128;

    f32x4 acc[4][4];
    #pragma unroll
    for (int mi = 0; mi < 4; ++mi)
        #pragma unroll
        for (int ni = 0; ni < 4; ++ni) acc[mi][ni] = (f32x4){0.f, 0.f, 0.f, 0.f};

    const int NT = K >> 5;
    int cur = 0;

    #pragma unroll
    for (int i = 0; i < 2; ++i) {
        const int ch = w * 64 + i * 256 + lane;
        const int r = ch >> 2, c = ch & 3;
        const int cg = c ^ ((r >> 1) & 3);
        gload_lds16(A + (arow0 + r) * K + cg * 8, &As[0][(w * 64 + i * 256) * 8]);
        gload_lds16(BT + (brow0 + r) * K + cg * 8, &Bs[0][(w * 64 + i * 256) * 8]);
    }
    __syncthreads();

    for (int t = 0; t < NT; ++t) {
        if (t + 1 < NT) {
            const int k0 = (t + 1) << 5;
            #pragma unroll
            for (int i = 0; i < 2; ++i) {
                const int ch = w * 64 + i * 256 + lane;
                const int r = ch >> 2, c = ch & 3;
                const int cg = c ^ ((r >> 1) & 3);
                gload_lds16(A + (arow0 + r) * K + k0 + cg * 8,
                            &As[cur ^ 1][(w * 64 + i * 256) * 8]);
                gload_lds16(BT + (brow0 + r) * K + k0 + cg * 8,
                            &Bs[cur ^ 1][(w * 64 + i * 256) * 8]);
            }
        }

        short8 af[4], bf[4];
        #pragma unroll
        for (int mi = 0; mi < 4; ++mi) {
            const int r = wm * 64 + mi * 16 + lq;
            af[mi] = *reinterpret_cast<const short8*>(
                &As[cur][r * 32 + ((lh ^ ((r >> 1) & 3)) * 8)]);
        }
        #pragma unroll
        for (int ni = 0; ni < 4; ++ni) {
            const int r = wn * 64 + ni * 16 + lq;
            bf[ni] = *reinterpret_cast<const short8*>(
                &Bs[cur][r * 32 + ((lh ^ ((r >> 1) & 3)) * 8)]);
        }
        #pragma unroll
        for (int mi = 0; mi < 4; ++mi)
            #pragma unroll
            for (int ni = 0; ni < 4; ++ni)
                acc[mi][ni] = __builtin_amdgcn_mfma_f32_16x16x32_bf16(
                    af[mi], bf[ni], acc[mi][ni], 0, 0, 0);

        __syncthreads();
        cur ^= 1;
    }

    #pragma unroll
    for (int mi = 0; mi < 4; ++mi) {
        const size_t row = arow0 + wm * 64 + mi * 16 + lh * 4;
        #pragma unroll
        for (int ni = 0; ni < 4; ++ni) {
            const size_t col = brow0 + wn * 64 + ni * 16 + lq;
            #pragma unroll
            for (int i = 0; i < 4; ++i)
                C[(row + i) * N + col] = acc[mi][ni][i];
        }
    }
}

// ---------------------------------------------------------------------------
// RoPE + RMSNorm on qkv f32 [B,T,1536] -> bf16 head-major.
//   q16: [B,16,T,64] (0.125*log2e folded -> attention uses exp2)
//   k16: [B, 4,T,64]
// ---------------------------------------------------------------------------
__global__ __launch_bounds__(256) void rope_rmsnorm_cast(
    const float* __restrict__ qkv, const float* __restrict__ cosb,
    const float* __restrict__ sinb, short* __restrict__ q16,
    short* __restrict__ k16, int B, int T) {
    const int lane = threadIdx.x & 63;
    const int wid  = threadIdx.x >> 6;
    const int row  = blockIdx.x * 4 + wid;
    const int bt = row / 20;
    const int h  = row % 20;
    const int b  = bt / T, t = bt % T;

    const float* src = (h < 16) ? qkv + (size_t)bt * 1536 + h * 64
                                : qkv + (size_t)bt * 1536 + 1024 + (h - 16) * 64;

    const int j = lane & 31;
    const float x1 = src[j];
    const float x2 = src[j + 32];
    const float c = cosb[t * 32 + j];
    const float s = sinb[t * 32 + j];
    float y = (lane < 32) ? (x1 * c + x2 * s) : (x2 * c - x1 * s);

    float ss = y * y;
    #pragma unroll
    for (int m = 1; m < 64; m <<= 1) ss += __shfl_xor(ss, m);
    const float r = rsqrtf(ss * (1.0f / 64.0f) + EPS);

    if (h < 16)
        q16[((size_t)(b * 16 + h) * T + t) * 64 + lane] = f2bf(y * r * (0.125f * LOG2E));
    else
        k16[((size_t)(b * 4 + (h - 16)) * T + t) * 64 + lane] = f2bf(y * r);
}

// ---------------------------------------------------------------------------
// v slice of qkv (f32, stride 1536) -> bf16 transposed + KEY-PERMUTED
// vT16 [B,4,64,T]: within each 32-key group, true key (hi*16 + g*4 + i)
// is stored at position (g*8 + hi*4 + i). This makes the PV MFMA A-fragment
// one contiguous 16B LDS read (k-map matches the in-register P fragment).
// ---------------------------------------------------------------------------
__global__ __launch_bounds__(256) void vcast_transpose(
    const float* __restrict__ qkv, short* __restrict__ vT, int B, int T) {
    __shared__ short tl[64][65];
    const int tid = threadIdx.x;
    const int b = blockIdx.z, kvh = blockIdx.y, t0 = blockIdx.x * 64;

    #pragma unroll
    for (int i = 0; i < 4; ++i) {
        const int tr = (tid >> 4) + i * 16;
        const int d4 = (tid & 15) * 4;
        const float4 v4 = *reinterpret_cast<const float4*>(
            &qkv[(size_t)(b * T + t0 + tr) * 1536 + 1280 + kvh * 64 + d4]);
        tl[tr][d4 + 0] = f2bf(v4.x);
        tl[tr][d4 + 1] = f2bf(v4.y);
        tl[tr][d4 + 2] = f2bf(v4.z);
        tl[tr][d4 + 3] = f2bf(v4.w);
    }
    __syncthreads();

    const int dim = tid >> 2;
    const int tq  = (tid & 3) * 16;      // covers keys tq..tq+15 (hi-half of a 32-group)
    const int hi  = (tq >> 4) & 1;
    const int a32 = tq & 32;
    short tmp[16];
    #pragma unroll
    for (int j2 = 0; j2 < 16; ++j2) tmp[j2] = tl[tq + j2][dim];
    short* orow = &vT[((size_t)(b * 4 + kvh) * 64 + dim) * T + t0];
    #pragma unroll
    for (int g = 0; g < 4; ++g) {
        *reinterpret_cast<short4v*>(orow + a32 + g * 8 + hi * 4) =
            *reinterpret_cast<short4v*>(&tmp[g * 4]);
    }
}

// ---------------------------------------------------------------------------
// softmax (exp2 units, defer-max) + PV for one 64-key tile.
// st: S^T scores (log2 units). yacc: Y^T accum. Vt: swizzled permuted V^T.
// ---------------------------------------------------------------------------
static __device__ __forceinline__ void sm_pv(f32x4 (&st)[4], f32x4 (&yacc)[4],
                                             float& mrun, float& lrun,
                                             const short* Vt,
                                             const int lq, const int lh) {
    float pm = -1e30f;
    #pragma unroll
    for (int ks = 0; ks < 4; ++ks)
        #pragma unroll
        for (int i2 = 0; i2 < 4; ++i2) pm = fmaxf(pm, st[ks][i2]);
    pm = fmaxf(pm, __shfl_xor(pm, 16));
    pm = fmaxf(pm, __shfl_xor(pm, 32));

    // defer-max (T13): skip yacc rescale while max growth <= 8 (log2 units)
    if (!__all(pm - mrun <= 8.0f)) {
        const float mn  = fmaxf(mrun, pm);
        const float fsc = exp2f(mrun - mn);
        #pragma unroll
        for (int dt = 0; dt < 4; ++dt) yacc[dt] *= fsc;
        lrun *= fsc;
        mrun = mn;
    }

    float ps = 0.f;
    #pragma unroll
    for (int ks = 0; ks < 4; ++ks)
        #pragma unroll
        for (int i2 = 0; i2 < 4; ++i2) {
            const float pv = exp2f(st[ks][i2] - mrun);
            st[ks][i2] = pv;
            ps += pv;
        }
    ps += __shfl_xor(ps, 16);
    ps += __shfl_xor(ps, 32);
    lrun += ps;

    // P -> bf16 fragments via packed cvt (compiler emits v_cvt_pk_bf16_f32)
    union { short8 s8; __hip_bfloat162 h2[4]; } pf[2];
    #pragma unroll
    for (int ks2 = 0; ks2 < 2; ++ks2) {
        pf[ks2].h2[0] = __float22bfloat162_rn(float2{st[2 * ks2][0], st[2 * ks2][1]});
        pf[ks2].h2[1] = __float22bfloat162_rn(float2{st[2 * ks2][2], st[2 * ks2][3]});
        pf[ks2].h2[2] = __float22bfloat162_rn(float2{st[2 * ks2 + 1][0], st[2 * ks2 + 1][1]});
        pf[ks2].h2[3] = __float22bfloat162_rn(float2{st[2 * ks2 + 1][2], st[2 * ks2 + 1][3]});
    }

    __builtin_amdgcn_s_setprio(1);
    #pragma unroll
    for (int dt = 0; dt < 4; ++dt) {
        const int rb = (dt * 16 + lq) * 128;
        const int sw = lq & 7;
        #pragma unroll
        for (int ks2 = 0; ks2 < 2; ++ks2) {
            const short8 vf = *reinterpret_cast<const short8*>(
                (const char*)Vt + rb + (((ks2 * 4 + lh) ^ sw) * 16));
            yacc[dt] = __builtin_amdgcn_mfma_f32_16x16x32_bf16(
                vf, pf[ks2].s8, yacc[dt], 0, 0, 0);
        }
    }
    __builtin_amdgcn_s_setprio(0);
}

// ---------------------------------------------------------------------------
// bf16 MFMA flash attention, unpaired q-tiles with LPT (longest-first) order.
// Grid: flat ( (T/64) * 16 * B ) blocks; idx -> (qb descending, b, h).
// Block qb stages qb+1 KV tiles; 4 waves x 16 q-rows.
// ---------------------------------------------------------------------------
__global__ __launch_bounds__(256) void attn_mfma(
    const short* __restrict__ q16, const short* __restrict__ k16,
    const short* __restrict__ vT16, short* __restrict__ att16, int B, int T) {
    __shared__ short Kt[64 * 64];
    __shared__ short Vt[64 * 64];

    const int tid  = threadIdx.x;
    const int lane = tid & 63;
    const int w    = tid >> 6;
    const int lq   = lane & 15;
    const int lh   = lane >> 4;

    const int nbh = 16 * B;
    const int idx = blockIdx.x;
    const int qb  = (T >> 6) - 1 - idx / nbh;   // longest-first
    const int bh  = idx % nbh;
    const int b   = bh >> 4, h = bh & 15;
    const int hk  = h >> 2;
    const int t0w = qb * 64 + w * 16;

    const short* qbase = q16 + (size_t)(b * 16 + h) * T * 64;
    const short8 qf0 = *reinterpret_cast<const short8*>(qbase + (t0w + lq) * 64 + lh * 8);
    const short8 qf1 = *reinterpret_cast<const short8*>(qbase + (t0w + lq) * 64 + 32 + lh * 8);

    const short* kgbase = k16 + (size_t)(b * 4 + hk) * T * 64;
    const short* vgbase = vT16 + (size_t)(b * 4 + hk) * 64 * T;

    f32x4 yacc[4];
    #pragma unroll
    for (int dt = 0; dt < 4; ++dt) yacc[dt] = (f32x4){0.f, 0.f, 0.f, 0.f};
    float mrun = -1e30f, lrun = 0.f;

    for (int ti = 0; ti <= qb; ++ti) {
        const int s0 = ti * 64;
        __syncthreads();
        #pragma unroll
        for (int i = 0; i < 2; ++i) {
            const int cid = tid + i * 256;
            const int r = cid >> 3, c = cid & 7;
            const short8 kv = *reinterpret_cast<const short8*>(
                kgbase + (size_t)(s0 + r) * 64 + c * 8);
            *reinterpret_cast<short8*>(
                (char*)Kt + r * 128 + ((c ^ (r & 7)) * 16)) = kv;
            const short8 vv = *reinterpret_cast<const short8*>(
                vgbase + (size_t)r * T + s0 + c * 8);
            *reinterpret_cast<short8*>(
                (char*)Vt + r * 128 + ((c ^ (r & 7)) * 16)) = vv;
        }
        __syncthreads();

        // --- QK^T: S^T[key][q] ---
        f32x4 st[4];
        __builtin_amdgcn_s_setprio(1);
        #pragma unroll
        for (int ks = 0; ks < 4; ++ks) {
            f32x4 a1 = (f32x4){0.f, 0.f, 0.f, 0.f};
            #pragma unroll
            for (int dk = 0; dk < 2; ++dk) {
                const short8 kfr = *reinterpret_cast<const short8*>(
                    (char*)Kt + (ks * 16 + lq) * 128 +
                    (((dk * 4 + lh) ^ (lq & 7)) * 16));
                a1 = __builtin_amdgcn_mfma_f32_16x16x32_bf16(
                    kfr, dk ? qf1 : qf0, a1, 0, 0, 0);
            }
            st[ks] = a1;
        }
        __builtin_amdgcn_s_setprio(0);

        // --- causal mask on diagonal tile ---
        if (ti == qb) {
            #pragma unroll
            for (int ks = 0; ks < 4; ++ks)
                #pragma unroll
                for (int i2 = 0; i2 < 4; ++i2)
                    if (ks * 16 + lh * 4 + i2 > w * 16 + lq)
                        st[ks][i2] = -1e30f;
        }

        sm_pv(st, yacc, mrun, lrun, Vt, lq, lh);
    }

    // --- epilogue: Y^T[dt*16+lh*4+i][q=lq] -> att16 [B,T,16,64] ---
    const float inv = 1.f / lrun;
    short* orow = att16 + (((size_t)b * T + t0w + lq) * 16 + h) * 64;
    #pragma unroll
    for (int dt = 0; dt < 4; ++dt) {
        short4v o;
        o[0] = f2bf(yacc[dt][0] * inv);
        o[1] = f2bf(yacc[dt][1] * inv);
        o[2] = f2bf(yacc[dt][2] * inv);
        o[3] = f2bf(yacc[dt][3] * inv);
        *reinterpret_cast<short4v*>(orow + dt * 16 + lh * 4) = o;
    }
}

// ---------------------------------------------------------------------------
extern "C" void kernel_launch(void* const* d_in, const int* in_sizes, int n_in,
                              void* d_out, int out_size, void* d_ws, size_t ws_size,
                              hipStream_t stream) {
    const float* x    = (const float*)d_in[0];
    const float* cosb = (const float*)d_in[1];
    const float* sinb = (const float*)d_in[2];
    const float* Wq   = (const float*)d_in[3];
    const float* Wk   = (const float*)d_in[4];
    const float* Wv   = (const float*)d_in[5];
    const float* Wo   = (const float*)d_in[6];
    float* out = (float*)d_out;

    const int B = 2, T = 2048;
    const int M = B * T;   // 4096
    const size_t MB = 1 << 20;

    char* wsb = (char*)d_ws;
    float* qkv  = (float*)(wsb);
    short* att16= (short*)(wsb);
    short* x16  = (short*)(wsb + 24 * MB);
    short* q16  = (short*)(wsb + 24 * MB);
    short* WT   = (short*)(wsb + 32 * MB);
    short* k16  = (short*)(wsb + 32 * MB);
    short* vT16 = (short*)(wsb + 34 * MB);
    short* WoT  = (short*)(wsb + 36 * MB);

    cast_f32_bf16<<<(M * 1024 / 8 + 255) / 256, 256, 0, stream>>>(x, x16, M * 1024 / 8);
    transpose_cast_w<<<dim3(16, 16), 256, 0, stream>>>(Wq, WT,               1024, 1024, 1024);
    transpose_cast_w<<<dim3(4, 16),  256, 0, stream>>>(Wk, WT + 1024 * 1024, 1024, 256,  1024);
    transpose_cast_w<<<dim3(4, 16),  256, 0, stream>>>(Wv, WT + 1280 * 1024, 1024, 256,  1024);
    transpose_cast_w<<<dim3(16, 16), 256, 0, stream>>>(Wo, WoT,              1024, 1024, 1024);

    gemm_bf16<<<dim3(1536 / 128, M / 128), 256, 0, stream>>>(x16, WT, qkv, M, 1536, 1024);

    rope_rmsnorm_cast<<<(B * T * 20) / 4, 256, 0, stream>>>(qkv, cosb, sinb, q16, k16, B, T);
    vcast_transpose<<<dim3(T / 64, 4, B), 256, 0, stream>>>(qkv, vT16, B, T);

    // unpaired flash attention, LPT (longest-first) flat grid
    attn_mfma<<<dim3((T / 64) * 16 * B), 256, 0, stream>>>(q16, k16, vT16, att16, B, T);

    gemm_bf16<<<dim3(1024 / 128, M / 128), 256, 0, stream>>>(att16, WoT, out, M, 1024, 1024);
}

// Round 6
// 129.926 us; speedup vs baseline: 15.7833x; 1.0699x over previous
//
#include <hip/hip_runtime.h>
#include <hip/hip_bf16.h>
#include <math.h>

#define EPS 1e-6f
#define LOG2E 1.44269504088896340736f

typedef __attribute__((ext_vector_type(8))) short short8;
typedef __attribute__((ext_vector_type(4))) short short4v;
typedef __attribute__((ext_vector_type(4))) float f32x4;

// f32 -> bf16 (round-to-nearest-even)
static __device__ __forceinline__ short f2bf(float x) {
    unsigned u = __builtin_bit_cast(unsigned, x);
    u += 0x7fffu + ((u >> 16) & 1u);
    return (short)(u >> 16);
}

typedef __attribute__((address_space(1))) const void gvoid_t;
typedef __attribute__((address_space(3))) void lvoid_t;
static __device__ __forceinline__ void gload_lds16(const void* g, void* l) {
    __builtin_amdgcn_global_load_lds((gvoid_t*)g, (lvoid_t*)l, 16, 0, 0);
}

// ---------------------------------------------------------------------------
// x f32 -> bf16, 8 elems/thread
// ---------------------------------------------------------------------------
__global__ __launch_bounds__(256) void cast_f32_bf16(const float* __restrict__ src,
                                                     short* __restrict__ dst, int n8) {
    const int i = blockIdx.x * 256 + threadIdx.x;
    if (i >= n8) return;
    const float4 a = reinterpret_cast<const float4*>(src)[2 * i];
    const float4 b = reinterpret_cast<const float4*>(src)[2 * i + 1];
    short8 o;
    o[0] = f2bf(a.x); o[1] = f2bf(a.y); o[2] = f2bf(a.z); o[3] = f2bf(a.w);
    o[4] = f2bf(b.x); o[5] = f2bf(b.y); o[6] = f2bf(b.z); o[7] = f2bf(b.w);
    reinterpret_cast<short8*>(dst)[i] = o;
}

// ---------------------------------------------------------------------------
// All four weight transposes in ONE dispatch.
// flat tile t: [0,256) Wq -> WT ; [256,320) Wk -> WT+1024*1024 ;
// [320,384) Wv -> WT+1280*1024 ; [384,640) Wo -> WoT.  All K=1024, Kd=1024.
// ---------------------------------------------------------------------------
__global__ __launch_bounds__(256) void transpose_cast_all(
    const float* __restrict__ Wq, const float* __restrict__ Wk,
    const float* __restrict__ Wv, const float* __restrict__ Wo,
    short* __restrict__ WT, short* __restrict__ WoT) {
    __shared__ short tl[64][65];
    int t = blockIdx.x;
    const float* src; short* dst; int N, nx;
    if (t < 256)      { src = Wq; dst = WT;                N = 1024; nx = 16; }
    else if (t < 320) { src = Wk; dst = WT + 1024 * 1024;  N = 256;  nx = 4;  t -= 256; }
    else if (t < 384) { src = Wv; dst = WT + 1280 * 1024;  N = 256;  nx = 4;  t -= 320; }
    else              { src = Wo; dst = WoT;               N = 1024; nx = 16; t -= 384; }
    const int n0 = (t % nx) * 64, k0 = (t / nx) * 64;
    const int tid = threadIdx.x;

    #pragma unroll
    for (int i = 0; i < 4; ++i) {
        const int kr = (tid >> 4) + i * 16;
        const int c4 = (tid & 15) * 4;
        const float4 v = *reinterpret_cast<const float4*>(
            &src[(size_t)(k0 + kr) * N + n0 + c4]);
        tl[kr][c4 + 0] = f2bf(v.x);
        tl[kr][c4 + 1] = f2bf(v.y);
        tl[kr][c4 + 2] = f2bf(v.z);
        tl[kr][c4 + 3] = f2bf(v.w);
    }
    __syncthreads();

    const int nr  = tid >> 2;
    const int kc0 = (tid & 3) * 16;
    short tmp[16];
    #pragma unroll
    for (int j = 0; j < 16; ++j) tmp[j] = tl[kc0 + j][nr];
    short8* outp = reinterpret_cast<short8*>(&dst[(size_t)(n0 + nr) * 1024 + k0 + kc0]);
    outp[0] = *reinterpret_cast<short8*>(&tmp[0]);
    outp[1] = *reinterpret_cast<short8*>(&tmp[8]);
}

// ---------------------------------------------------------------------------
// bf16 MFMA GEMM: C[M,N] f32 = A[M,K] bf16 · B^T[N,K] bf16.  (unchanged)
// ---------------------------------------------------------------------------
__global__ __launch_bounds__(256) void gemm_bf16(const short* __restrict__ A,
                                                 const short* __restrict__ BT,
                                                 float* __restrict__ C,
                                                 int M, int N, int K) {
    __shared__ short As[2][128 * 32];
    __shared__ short Bs[2][128 * 32];

    const int tid  = threadIdx.x;
    const int lane = tid & 63;
    const int w    = tid >> 6;
    const int lq = lane & 15, lh = lane >> 4;
    const int wm = w >> 1,   wn = w & 1;
    const size_t arow0 = (size_t)blockIdx.y * 128;
    const size_t brow0 = (size_t)blockIdx.x * 128;

    f32x4 acc[4][4];
    #pragma unroll
    for (int mi = 0; mi < 4; ++mi)
        #pragma unroll
        for (int ni = 0; ni < 4; ++ni) acc[mi][ni] = (f32x4){0.f, 0.f, 0.f, 0.f};

    const int NT = K >> 5;
    int cur = 0;

    #pragma unroll
    for (int i = 0; i < 2; ++i) {
        const int ch = w * 64 + i * 256 + lane;
        const int r = ch >> 2, c = ch & 3;
        const int cg = c ^ ((r >> 1) & 3);
        gload_lds16(A + (arow0 + r) * K + cg * 8, &As[0][(w * 64 + i * 256) * 8]);
        gload_lds16(BT + (brow0 + r) * K + cg * 8, &Bs[0][(w * 64 + i * 256) * 8]);
    }
    __syncthreads();

    for (int t = 0; t < NT; ++t) {
        if (t + 1 < NT) {
            const int k0 = (t + 1) << 5;
            #pragma unroll
            for (int i = 0; i < 2; ++i) {
                const int ch = w * 64 + i * 256 + lane;
                const int r = ch >> 2, c = ch & 3;
                const int cg = c ^ ((r >> 1) & 3);
                gload_lds16(A + (arow0 + r) * K + k0 + cg * 8,
                            &As[cur ^ 1][(w * 64 + i * 256) * 8]);
                gload_lds16(BT + (brow0 + r) * K + k0 + cg * 8,
                            &Bs[cur ^ 1][(w * 64 + i * 256) * 8]);
            }
        }

        short8 af[4], bf[4];
        #pragma unroll
        for (int mi = 0; mi < 4; ++mi) {
            const int r = wm * 64 + mi * 16 + lq;
            af[mi] = *reinterpret_cast<const short8*>(
                &As[cur][r * 32 + ((lh ^ ((r >> 1) & 3)) * 8)]);
        }
        #pragma unroll
        for (int ni = 0; ni < 4; ++ni) {
            const int r = wn * 64 + ni * 16 + lq;
            bf[ni] = *reinterpret_cast<const short8*>(
                &Bs[cur][r * 32 + ((lh ^ ((r >> 1) & 3)) * 8)]);
        }
        #pragma unroll
        for (int mi = 0; mi < 4; ++mi)
            #pragma unroll
            for (int ni = 0; ni < 4; ++ni)
                acc[mi][ni] = __builtin_amdgcn_mfma_f32_16x16x32_bf16(
                    af[mi], bf[ni], acc[mi][ni], 0, 0, 0);

        __syncthreads();
        cur ^= 1;
    }

    #pragma unroll
    for (int mi = 0; mi < 4; ++mi) {
        const size_t row = arow0 + wm * 64 + mi * 16 + lh * 4;
        #pragma unroll
        for (int ni = 0; ni < 4; ++ni) {
            const size_t col = brow0 + wn * 64 + ni * 16 + lq;
            #pragma unroll
            for (int i = 0; i < 4; ++i)
                C[(row + i) * N + col] = acc[mi][ni][i];
        }
    }
}

// ---------------------------------------------------------------------------
// RoPE + RMSNorm on qkv f32 [B,T,1536] -> bf16 head-major.
//   q16: [B,16,T,64] (0.125*log2e folded -> attention uses exp2)
//   k16: [B, 4,T,64]
// ---------------------------------------------------------------------------
__global__ __launch_bounds__(256) void rope_rmsnorm_cast(
    const float* __restrict__ qkv, const float* __restrict__ cosb,
    const float* __restrict__ sinb, short* __restrict__ q16,
    short* __restrict__ k16, int B, int T) {
    const int lane = threadIdx.x & 63;
    const int wid  = threadIdx.x >> 6;
    const int row  = blockIdx.x * 4 + wid;
    const int bt = row / 20;
    const int h  = row % 20;
    const int b  = bt / T, t = bt % T;

    const float* src = (h < 16) ? qkv + (size_t)bt * 1536 + h * 64
                                : qkv + (size_t)bt * 1536 + 1024 + (h - 16) * 64;

    const int j = lane & 31;
    const float x1 = src[j];
    const float x2 = src[j + 32];
    const float c = cosb[t * 32 + j];
    const float s = sinb[t * 32 + j];
    float y = (lane < 32) ? (x1 * c + x2 * s) : (x2 * c - x1 * s);

    float ss = y * y;
    #pragma unroll
    for (int m = 1; m < 64; m <<= 1) ss += __shfl_xor(ss, m);
    const float r = rsqrtf(ss * (1.0f / 64.0f) + EPS);

    if (h < 16)
        q16[((size_t)(b * 16 + h) * T + t) * 64 + lane] = f2bf(y * r * (0.125f * LOG2E));
    else
        k16[((size_t)(b * 4 + (h - 16)) * T + t) * 64 + lane] = f2bf(y * r);
}

// ---------------------------------------------------------------------------
// v slice of qkv (f32, stride 1536) -> bf16 transposed + KEY-PERMUTED
// vT16 [B,4,64,T]: within each 32-key group, true key (hi*16 + g*4 + i)
// stored at (g*8 + hi*4 + i)  => PV A-fragment is one contiguous 16B read.
// ---------------------------------------------------------------------------
__global__ __launch_bounds__(256) void vcast_transpose(
    const float* __restrict__ qkv, short* __restrict__ vT, int B, int T) {
    __shared__ short tl[64][65];
    const int tid = threadIdx.x;
    const int b = blockIdx.z, kvh = blockIdx.y, t0 = blockIdx.x * 64;

    #pragma unroll
    for (int i = 0; i < 4; ++i) {
        const int tr = (tid >> 4) + i * 16;
        const int d4 = (tid & 15) * 4;
        const float4 v4 = *reinterpret_cast<const float4*>(
            &qkv[(size_t)(b * T + t0 + tr) * 1536 + 1280 + kvh * 64 + d4]);
        tl[tr][d4 + 0] = f2bf(v4.x);
        tl[tr][d4 + 1] = f2bf(v4.y);
        tl[tr][d4 + 2] = f2bf(v4.z);
        tl[tr][d4 + 3] = f2bf(v4.w);
    }
    __syncthreads();

    const int dim = tid >> 2;
    const int tq  = (tid & 3) * 16;
    const int hi  = (tq >> 4) & 1;
    const int a32 = tq & 32;
    short tmp[16];
    #pragma unroll
    for (int j2 = 0; j2 < 16; ++j2) tmp[j2] = tl[tq + j2][dim];
    short* orow = &vT[((size_t)(b * 4 + kvh) * 64 + dim) * T + t0];
    #pragma unroll
    for (int g = 0; g < 4; ++g) {
        *reinterpret_cast<short4v*>(orow + a32 + g * 8 + hi * 4) =
            *reinterpret_cast<short4v*>(&tmp[g * 4]);
    }
}

// ---------------------------------------------------------------------------
// bf16 MFMA flash attention — STATIC-MAX softmax (scores bounded: RMSNorm'd
// q,k => |s*log2e| <= 11.6, so p = exp2(s) directly; no running max, no
// rescale). l accumulated via an extra MFMA with a ones A-fragment.
// 128-thread (2-wave) blocks, 32 q-rows/block, LPT grid of 2048 blocks.
// K/V staged via global_load_lds with pre-swizzled global source.
// ---------------------------------------------------------------------------
__global__ __launch_bounds__(128) void attn_mfma(
    const short* __restrict__ q16, const short* __restrict__ k16,
    const short* __restrict__ vT16, short* __restrict__ att16, int B, int T) {
    __shared__ short Kt[64 * 64];
    __shared__ short Vt[64 * 64];

    const int tid  = threadIdx.x;
    const int lane = tid & 63;
    const int w    = tid >> 6;          // 0..1
    const int lq   = lane & 15;
    const int lh   = lane >> 4;

    const int nbh = 16 * B;             // 32
    const int idx = blockIdx.x;
    const int qs  = (T >> 5) - 1 - idx / nbh;   // 63..0, longest-first
    const int bh  = idx % nbh;
    const int b   = bh >> 4, h = bh & 15;
    const int hk  = h >> 2;
    const int t0w = qs * 32 + w * 16;
    const int nt  = (qs >> 1) + 1;
    const bool evenq = !(qs & 1);       // last tile: keys 32..63 fully masked

    const short* qbase = q16 + (size_t)(b * 16 + h) * T * 64;
    const short8 qf0 = *reinterpret_cast<const short8*>(qbase + (t0w + lq) * 64 + lh * 8);
    const short8 qf1 = *reinterpret_cast<const short8*>(qbase + (t0w + lq) * 64 + 32 + lh * 8);

    const short* kgbase = k16 + (size_t)(b * 4 + hk) * T * 64;
    const short* vgbase = vT16 + (size_t)(b * 4 + hk) * 64 * T;

    // staging decomposition: lane -> (row-in-8group, chunk); source pre-swizzled
    const int sr  = lane >> 3;          // 0..7
    const int sc  = lane & 7;
    const int scg = sc ^ sr;            // global chunk to fetch (inverse swizzle)

    short8 ones;
    #pragma unroll
    for (int i = 0; i < 8; ++i) ones[i] = (short)0x3F80;   // bf16 1.0

    f32x4 yacc[4];
    #pragma unroll
    for (int dt = 0; dt < 4; ++dt) yacc[dt] = (f32x4){0.f, 0.f, 0.f, 0.f};
    f32x4 lacc = (f32x4){0.f, 0.f, 0.f, 0.f};

    for (int ti = 0; ti < nt; ++ti) {
        const int s0 = ti * 64;
        const bool last = (ti == nt - 1);
        const int kmax = (last && evenq) ? 2 : 4;   // skip fully-masked half
        __syncthreads();
        #pragma unroll
        for (int p2 = 0; p2 < 4; ++p2) {
            const int r = w * 32 + p2 * 8 + sr;
            gload_lds16(kgbase + (size_t)(s0 + r) * 64 + scg * 8,
                        &Kt[(w * 32 + p2 * 8) * 64]);
            gload_lds16(vgbase + (size_t)r * T + s0 + scg * 8,
                        &Vt[(w * 32 + p2 * 8) * 64]);
        }
        __syncthreads();

        // --- QK^T: S^T[key][q] (log2 units; scale folded into q) ---
        f32x4 st[4];
        __builtin_amdgcn_s_setprio(1);
        #pragma unroll
        for (int ks = 0; ks < 4; ++ks) if (ks < kmax) {
            f32x4 a1 = (f32x4){0.f, 0.f, 0.f, 0.f};
            #pragma unroll
            for (int dk = 0; dk < 2; ++dk) {
                const short8 kfr = *reinterpret_cast<const short8*>(
                    (char*)Kt + (ks * 16 + lq) * 128 +
                    (((dk * 4 + lh) ^ (lq & 7)) * 16));
                a1 = __builtin_amdgcn_mfma_f32_16x16x32_bf16(
                    kfr, dk ? qf1 : qf0, a1, 0, 0, 0);
            }
            st[ks] = a1;
        }
        __builtin_amdgcn_s_setprio(0);

        // --- causal mask on diagonal tile ---
        if (last) {
            const int rloc = (qs & 1) * 32 + w * 16 + lq;
            #pragma unroll
            for (int ks = 0; ks < 4; ++ks) if (ks < kmax)
                #pragma unroll
                for (int i2 = 0; i2 < 4; ++i2)
                    if (ks * 16 + lh * 4 + i2 > rloc)
                        st[ks][i2] = -1e30f;
        }

        // --- p = exp2(s) directly (bounded scores); pack to bf16 ---
        union { short8 s8; __hip_bfloat162 h2[4]; } pf[2];
        #pragma unroll
        for (int ks2 = 0; ks2 < 2; ++ks2) if (ks2 * 2 < kmax) {
            #pragma unroll
            for (int ks = 2 * ks2; ks < 2 * ks2 + 2; ++ks)
                #pragma unroll
                for (int i2 = 0; i2 < 4; ++i2)
                    st[ks][i2] = exp2f(st[ks][i2]);
            pf[ks2].h2[0] = __float22bfloat162_rn(float2{st[2 * ks2][0], st[2 * ks2][1]});
            pf[ks2].h2[1] = __float22bfloat162_rn(float2{st[2 * ks2][2], st[2 * ks2][3]});
            pf[ks2].h2[2] = __float22bfloat162_rn(float2{st[2 * ks2 + 1][0], st[2 * ks2 + 1][1]});
            pf[ks2].h2[3] = __float22bfloat162_rn(float2{st[2 * ks2 + 1][2], st[2 * ks2 + 1][3]});
        }

        // --- PV + l (ones-fragment MFMA) ---
        __builtin_amdgcn_s_setprio(1);
        #pragma unroll
        for (int ks2 = 0; ks2 < 2; ++ks2) if (ks2 * 2 < kmax)
            lacc = __builtin_amdgcn_mfma_f32_16x16x32_bf16(ones, pf[ks2].s8, lacc, 0, 0, 0);
        #pragma unroll
        for (int dt = 0; dt < 4; ++dt) {
            const int rb = (dt * 16 + lq) * 128;
            const int sw = lq & 7;
            #pragma unroll
            for (int ks2 = 0; ks2 < 2; ++ks2) if (ks2 * 2 < kmax) {
                const short8 vf = *reinterpret_cast<const short8*>(
                    (const char*)Vt + rb + (((ks2 * 4 + lh) ^ sw) * 16));
                yacc[dt] = __builtin_amdgcn_mfma_f32_16x16x32_bf16(
                    vf, pf[ks2].s8, yacc[dt], 0, 0, 0);
            }
        }
        __builtin_amdgcn_s_setprio(0);
    }

    // --- epilogue: all lacc components equal Σp for column lq ---
    const float inv = 1.f / lacc[0];
    short* orow = att16 + (((size_t)b * T + t0w + lq) * 16 + h) * 64;
    #pragma unroll
    for (int dt = 0; dt < 4; ++dt) {
        short4v o;
        o[0] = f2bf(yacc[dt][0] * inv);
        o[1] = f2bf(yacc[dt][1] * inv);
        o[2] = f2bf(yacc[dt][2] * inv);
        o[3] = f2bf(yacc[dt][3] * inv);
        *reinterpret_cast<short4v*>(orow + dt * 16 + lh * 4) = o;
    }
}

// ---------------------------------------------------------------------------
extern "C" void kernel_launch(void* const* d_in, const int* in_sizes, int n_in,
                              void* d_out, int out_size, void* d_ws, size_t ws_size,
                              hipStream_t stream) {
    const float* x    = (const float*)d_in[0];
    const float* cosb = (const float*)d_in[1];
    const float* sinb = (const float*)d_in[2];
    const float* Wq   = (const float*)d_in[3];
    const float* Wk   = (const float*)d_in[4];
    const float* Wv   = (const float*)d_in[5];
    const float* Wo   = (const float*)d_in[6];
    float* out = (float*)d_out;

    const int B = 2, T = 2048;
    const int M = B * T;   // 4096
    const size_t MB = 1 << 20;

    char* wsb = (char*)d_ws;
    float* qkv  = (float*)(wsb);
    short* att16= (short*)(wsb);
    short* x16  = (short*)(wsb + 24 * MB);
    short* q16  = (short*)(wsb + 24 * MB);
    short* WT   = (short*)(wsb + 32 * MB);
    short* k16  = (short*)(wsb + 32 * MB);
    short* vT16 = (short*)(wsb + 34 * MB);
    short* WoT  = (short*)(wsb + 36 * MB);

    cast_f32_bf16<<<(M * 1024 / 8 + 255) / 256, 256, 0, stream>>>(x, x16, M * 1024 / 8);
    transpose_cast_all<<<640, 256, 0, stream>>>(Wq, Wk, Wv, Wo, WT, WoT);

    gemm_bf16<<<dim3(1536 / 128, M / 128), 256, 0, stream>>>(x16, WT, qkv, M, 1536, 1024);

    rope_rmsnorm_cast<<<(B * T * 20) / 4, 256, 0, stream>>>(qkv, cosb, sinb, q16, k16, B, T);
    vcast_transpose<<<dim3(T / 64, 4, B), 256, 0, stream>>>(qkv, vT16, B, T);

    // flash attention: 2-wave blocks, 32 q-rows each, LPT flat grid
    attn_mfma<<<dim3((T / 32) * 16 * B), 128, 0, stream>>>(q16, k16, vT16, att16, B, T);

    gemm_bf16<<<dim3(1024 / 128, M / 128), 256, 0, stream>>>(att16, WoT, out, M, 1024, 1024);
}